// Round 1
// baseline (2178.941 us; speedup 1.0000x reference)
//
#include <hip/hip_runtime.h>
#include <math.h>

#define N_NODES 50000
#define E_REAL  200000
#define E_MEAN  250000   // real edges + self-loops (relation 0)
#define NREL    65
#define HDIM    256
#define NGRAPH  1600
#define EB      16       // edges (or nodes) per block

// decode combined edge id: [0,E_REAL) real edges, [E_REAL,E_MEAN) self loops (rel 0)
__device__ __forceinline__ void decode_edge(int e, const int* __restrict__ src,
                                            const int* __restrict__ dst,
                                            const int* __restrict__ et,
                                            int& s, int& d, int& r) {
    if (e < E_REAL) { s = src[e]; d = dst[e]; r = et[e]; }
    else            { s = d = e - E_REAL; r = 0; }
}

__global__ void count_kernel(const int* __restrict__ src, const int* __restrict__ dst,
                             const int* __restrict__ et, int* __restrict__ cnt,
                             int* __restrict__ hist) {
    __shared__ int lhist[NREL];
    int t = threadIdx.x;
    if (t < NREL) lhist[t] = 0;
    __syncthreads();
    int e = blockIdx.x * blockDim.x + t;
    if (e < E_MEAN) {
        int s, d, r; decode_edge(e, src, dst, et, s, d, r);
        atomicAdd(&cnt[d * NREL + r], 1);
        atomicAdd(&lhist[r], 1);
    }
    __syncthreads();
    if (t < NREL && lhist[t] > 0) atomicAdd(&hist[t], lhist[t]);
}

__global__ void scan_kernel(const int* __restrict__ hist, int* __restrict__ cursor) {
    int acc = 0;
    for (int r = 0; r < NREL; ++r) { cursor[r] = acc; acc += hist[r]; }
}

__global__ void scatter_kernel(const int* __restrict__ src, const int* __restrict__ dst,
                               const int* __restrict__ et, int* __restrict__ cursor,
                               int* __restrict__ perm) {
    int e = blockIdx.x * blockDim.x + threadIdx.x;
    if (e < E_MEAN) {
        int s, d, r; decode_edge(e, src, dst, et, s, d, r);
        int pos = atomicAdd(&cursor[r], 1);
        perm[pos] = e;
    }
}

// out[i][t] = bias[t] + sum_k act(in[i][k]) * root[k][t]   (16 nodes/block, t = column)
template<int F, bool RELU_IN>
__global__ void init_gemm(const float* __restrict__ in, const float* __restrict__ root,
                          const float* __restrict__ bias, float* __restrict__ out) {
    __shared__ float xs[EB][F];
    int t = threadIdx.x;
    int base = blockIdx.x * EB;
    for (int e = 0; e < EB; ++e)
        for (int idx = t; idx < F; idx += 256) {
            float v = in[(size_t)(base + e) * F + idx];
            xs[e][idx] = RELU_IN ? fmaxf(v, 0.f) : v;
        }
    __syncthreads();
    float acc[EB];
    float bv = bias[t];
#pragma unroll
    for (int e = 0; e < EB; ++e) acc[e] = bv;
    for (int k = 0; k < F; ++k) {
        float wv = root[k * HDIM + t];
#pragma unroll
        for (int e = 0; e < EB; ++e) acc[e] += xs[e][k] * wv;
    }
    for (int e = 0; e < EB; ++e) out[(size_t)(base + e) * HDIM + t] = acc[e];
}

// per edge: out[dst] += (act(in[src]) @ W[et]) / cnt[dst,et]  (16 edges/block, sorted by rel)
template<int F, bool RELU_IN>
__global__ void edge_gemm(const float* __restrict__ in, const float* __restrict__ W,
                          const int* __restrict__ srcA, const int* __restrict__ dstA,
                          const int* __restrict__ etA, const int* __restrict__ perm,
                          const int* __restrict__ cnt, float* __restrict__ out) {
    __shared__ float xs[EB][F];
    __shared__ int ssrc[EB], sdst[EB], srel[EB];
    __shared__ float sw[EB];
    int t = threadIdx.x;
    int base = blockIdx.x * EB;
    if (t < EB) {
        int e = perm[base + t];
        int s, d, r; decode_edge(e, srcA, dstA, etA, s, d, r);
        ssrc[t] = s; sdst[t] = d; srel[t] = r;
        sw[t] = 1.0f / (float)cnt[d * NREL + r];
    }
    __syncthreads();
    for (int e = 0; e < EB; ++e) {
        int s = ssrc[e];
        for (int idx = t; idx < F; idx += 256) {
            float v = in[(size_t)s * F + idx];
            xs[e][idx] = RELU_IN ? fmaxf(v, 0.f) : v;
        }
    }
    __syncthreads();
    int r0 = srel[0];
    bool uni = true;
    for (int e = 1; e < EB; ++e) uni = uni && (srel[e] == r0);
    if (uni) {
        const float* Wp = W + (size_t)r0 * F * HDIM;
        float acc[EB];
#pragma unroll
        for (int e = 0; e < EB; ++e) acc[e] = 0.f;
        for (int k = 0; k < F; ++k) {
            float wv = Wp[k * HDIM + t];
#pragma unroll
            for (int e = 0; e < EB; ++e) acc[e] += xs[e][k] * wv;
        }
        for (int e = 0; e < EB; ++e)
            atomicAdd(&out[(size_t)sdst[e] * HDIM + t], acc[e] * sw[e]);
    } else {
        for (int e = 0; e < EB; ++e) {
            const float* Wp = W + (size_t)srel[e] * F * HDIM;
            float a = 0.f;
            for (int k = 0; k < F; ++k) a += xs[e][k] * Wp[k * HDIM + t];
            atomicAdd(&out[(size_t)sdst[e] * HDIM + t], a * sw[e]);
        }
    }
}

// w = sigmoid(relu(h)·ws_w + ws_b); emb[batch[i]] += w * relu(h)
__global__ void pool_kernel(const float* __restrict__ h, const int* __restrict__ batch,
                            const float* __restrict__ wsw, const float* __restrict__ wsb,
                            float* __restrict__ emb) {
    int i = blockIdx.x;
    int t = threadIdx.x;
    float v = fmaxf(h[(size_t)i * HDIM + t], 0.f);
    float p = v * wsw[t];
    for (int off = 32; off >= 1; off >>= 1) p += __shfl_down(p, off, 64);
    __shared__ float red[4];
    __shared__ float ssig;
    if ((t & 63) == 0) red[t >> 6] = p;
    __syncthreads();
    if (t == 0) {
        float s = red[0] + red[1] + red[2] + red[3] + wsb[0];
        ssig = 1.0f / (1.0f + expf(-s));
    }
    __syncthreads();
    atomicAdd(&emb[(size_t)batch[i] * HDIM + t], ssig * v);
}

__global__ void mlp_kernel(const float* __restrict__ emb,
                           const float* __restrict__ m1w, const float* __restrict__ m1b,
                           const float* __restrict__ m2w, const float* __restrict__ m2b,
                           const float* __restrict__ m3w, const float* __restrict__ m3b,
                           const float* __restrict__ ow,  const float* __restrict__ ob,
                           float* __restrict__ out) {
    int g = blockIdx.x;
    int t = threadIdx.x; // 64 threads = 1 wave
    __shared__ float e[HDIM];
    __shared__ float z1[64], z2[64];
    for (int idx = t; idx < HDIM; idx += 64) e[idx] = emb[(size_t)g * HDIM + idx];
    __syncthreads();
    float a = m1b[t];
    for (int k = 0; k < HDIM; ++k) a += e[k] * m1w[k * 64 + t];
    z1[t] = fmaxf(a, 0.f);
    __syncthreads();
    a = m2b[t];
    for (int k = 0; k < 64; ++k) a += z1[k] * m2w[k * 64 + t];
    z2[t] = fmaxf(a, 0.f);
    __syncthreads();
    a = m3b[t];
    for (int k = 0; k < 64; ++k) a += z2[k] * m3w[k * 64 + t];
    float p = a * ow[t];
    for (int off = 32; off >= 1; off >>= 1) p += __shfl_down(p, off, 64);
    if (t == 0) out[g] = p + ob[0];
}

extern "C" void kernel_launch(void* const* d_in, const int* in_sizes, int n_in,
                              void* d_out, int out_size, void* d_ws, size_t ws_size,
                              hipStream_t stream) {
    const float* x     = (const float*)d_in[0];
    const int*   ei    = (const int*)d_in[1];
    const int*   src   = ei;
    const int*   dst   = ei + E_REAL;
    const int*   et    = (const int*)d_in[2];
    const int*   batch = (const int*)d_in[3];
    const float* W1    = (const float*)d_in[4];
    const float* root1 = (const float*)d_in[5];
    const float* b1    = (const float*)d_in[6];
    const float* W2    = (const float*)d_in[7];
    const float* root2 = (const float*)d_in[8];
    const float* b2    = (const float*)d_in[9];
    const float* wsw   = (const float*)d_in[10];
    const float* wsb   = (const float*)d_in[11];
    const float* m1w   = (const float*)d_in[12];
    const float* m1b   = (const float*)d_in[13];
    const float* m2w   = (const float*)d_in[14];
    const float* m2b   = (const float*)d_in[15];
    const float* m3w   = (const float*)d_in[16];
    const float* m3b   = (const float*)d_in[17];
    const float* ow    = (const float*)d_in[18];
    const float* ob    = (const float*)d_in[19];

    char* ws = (char*)d_ws;
    size_t off = 0;
    auto alloc = [&](size_t bytes) {
        void* p = ws + off;
        off = (off + bytes + 255) & ~(size_t)255;
        return p;
    };
    int*   cnt    = (int*)alloc((size_t)N_NODES * NREL * 4);   // 13.0 MB
    int*   hist   = (int*)alloc(NREL * 4);
    int*   cursor = (int*)alloc(NREL * 4);
    int*   perm   = (int*)alloc((size_t)E_MEAN * 4);           // 1.0 MB
    float* h1     = (float*)alloc((size_t)N_NODES * HDIM * 4); // 51.2 MB
    float* h2     = (float*)alloc((size_t)N_NODES * HDIM * 4); // 51.2 MB
    float* emb    = (float*)alloc((size_t)NGRAPH * HDIM * 4);  // 1.6 MB

    hipMemsetAsync(cnt, 0, (size_t)N_NODES * NREL * 4, stream);
    hipMemsetAsync(hist, 0, NREL * 4, stream);
    hipMemsetAsync(emb, 0, (size_t)NGRAPH * HDIM * 4, stream);

    count_kernel<<<(E_MEAN + 255) / 256, 256, 0, stream>>>(src, dst, et, cnt, hist);
    scan_kernel<<<1, 1, 0, stream>>>(hist, cursor);
    scatter_kernel<<<(E_MEAN + 255) / 256, 256, 0, stream>>>(src, dst, et, cursor, perm);

    // layer 1: h1 = x @ root1 + b1 ; += per-relation mean messages
    init_gemm<128, false><<<N_NODES / EB, 256, 0, stream>>>(x, root1, b1, h1);
    edge_gemm<128, false><<<E_MEAN / EB, 256, 0, stream>>>(x, W1, src, dst, et, perm, cnt, h1);
    // layer 2: input relu(h1)
    init_gemm<256, true><<<N_NODES / EB, 256, 0, stream>>>(h1, root2, b2, h2);
    edge_gemm<256, true><<<E_MEAN / EB, 256, 0, stream>>>(h1, W2, src, dst, et, perm, cnt, h2);

    pool_kernel<<<N_NODES, 256, 0, stream>>>(h2, batch, wsw, wsb, emb);
    mlp_kernel<<<NGRAPH, 64, 0, stream>>>(emb, m1w, m1b, m2w, m2b, m3w, m3b, ow, ob, (float*)d_out);
}

// Round 2
// 1340.577 us; speedup vs baseline: 1.6254x; 1.6254x over previous
//
#include <hip/hip_runtime.h>
#include <math.h>

#define N_NODES 50000
#define E_REAL  200000
#define E_MEAN  250000   // real edges + self-loops (relation 0)
#define NREL    65
#define HDIM    256
#define NGRAPH  1600
#define EB      16       // edges (or nodes) per block
#define NB_E    ((E_MEAN + 255) / 256)   // 977 blocks over edges
#define TOT_HIST (NREL * NB_E)           // 63505

// decode combined edge id: [0,E_REAL) real edges, [E_REAL,E_MEAN) self loops (rel 0)
__device__ __forceinline__ void decode_edge(int e, const int* __restrict__ src,
                                            const int* __restrict__ dst,
                                            const int* __restrict__ et,
                                            int& s, int& d, int& r) {
    if (e < E_REAL) { s = src[e]; d = dst[e]; r = et[e]; }
    else            { s = d = e - E_REAL; r = 0; }
}

// per-(dst,rel) counts for mean normalization + per-block relation histogram
// blockHist layout: relation-major [r][b] so a linear exclusive scan gives
// exactly the perm base offsets for counting sort.
__global__ void count_kernel(const int* __restrict__ src, const int* __restrict__ dst,
                             const int* __restrict__ et, int* __restrict__ cnt,
                             int* __restrict__ blockHist) {
    __shared__ int lhist[NREL];
    int t = threadIdx.x;
    if (t < NREL) lhist[t] = 0;
    __syncthreads();
    int e = blockIdx.x * blockDim.x + t;
    if (e < E_MEAN) {
        int s, d, r; decode_edge(e, src, dst, et, s, d, r);
        atomicAdd(&cnt[d * NREL + r], 1);
        atomicAdd(&lhist[r], 1);
    }
    __syncthreads();
    if (t < NREL) blockHist[t * NB_E + blockIdx.x] = lhist[t];
}

// single-block exclusive scan of blockHist (TOT_HIST ints) -> base
__global__ void scan_kernel(const int* __restrict__ in, int* __restrict__ out) {
    const int T = 1024;
    int t = threadIdx.x;
    const int per = (TOT_HIST + T - 1) / T;  // 63
    int start = t * per;
    int end = start + per; if (end > TOT_HIST) end = TOT_HIST;
    int s = 0;
    for (int i = start; i < end && i < TOT_HIST; ++i) s += in[i];
    __shared__ int sums[1024];
    sums[t] = s;
    __syncthreads();
    for (int off = 1; off < 1024; off <<= 1) {
        int v = (t >= off) ? sums[t - off] : 0;
        __syncthreads();
        sums[t] += v;
        __syncthreads();
    }
    int acc = (t == 0) ? 0 : sums[t - 1];
    for (int i = start; i < end && i < TOT_HIST; ++i) {
        int v = in[i];
        out[i] = acc;
        acc += v;
    }
}

// counting-sort scatter: local rank via LDS atomics (block-local, uncontended
// globally), position = base[r][block] + local rank.
__global__ void scatter_sorted(const int* __restrict__ src, const int* __restrict__ dst,
                               const int* __restrict__ et, const int* __restrict__ base,
                               int* __restrict__ perm) {
    __shared__ int lhist[NREL];
    int t = threadIdx.x;
    int b = blockIdx.x;
    if (t < NREL) lhist[t] = 0;
    __syncthreads();
    int e = b * 256 + t;
    if (e < E_MEAN) {
        int s, d, r; decode_edge(e, src, dst, et, s, d, r);
        int local = atomicAdd(&lhist[r], 1);
        perm[base[r * NB_E + b] + local] = e;
    }
}

// out[i][t] = bias[t] + sum_k act(in[i][k]) * root[k][t]   (16 nodes/block, t = column)
template<int F, bool RELU_IN>
__global__ void init_gemm(const float* __restrict__ in, const float* __restrict__ root,
                          const float* __restrict__ bias, float* __restrict__ out) {
    __shared__ float xs[EB][F];
    int t = threadIdx.x;
    int base = blockIdx.x * EB;
    for (int e = 0; e < EB; ++e)
        for (int idx = t; idx < F; idx += 256) {
            float v = in[(size_t)(base + e) * F + idx];
            xs[e][idx] = RELU_IN ? fmaxf(v, 0.f) : v;
        }
    __syncthreads();
    float acc[EB];
    float bv = bias[t];
#pragma unroll
    for (int e = 0; e < EB; ++e) acc[e] = bv;
    for (int k = 0; k < F; ++k) {
        float wv = root[k * HDIM + t];
#pragma unroll
        for (int e = 0; e < EB; ++e) acc[e] += xs[e][k] * wv;
    }
    for (int e = 0; e < EB; ++e) out[(size_t)(base + e) * HDIM + t] = acc[e];
}

// per edge: out[dst] += (act(in[src]) @ W[et]) / cnt[dst,et]  (16 edges/block, sorted by rel)
template<int F, bool RELU_IN>
__global__ void edge_gemm(const float* __restrict__ in, const float* __restrict__ W,
                          const int* __restrict__ srcA, const int* __restrict__ dstA,
                          const int* __restrict__ etA, const int* __restrict__ perm,
                          const int* __restrict__ cnt, float* __restrict__ out) {
    __shared__ float xs[EB][F];
    __shared__ int ssrc[EB], sdst[EB], srel[EB];
    __shared__ float sw[EB];
    int t = threadIdx.x;
    int base = blockIdx.x * EB;
    if (t < EB) {
        int e = perm[base + t];
        int s, d, r; decode_edge(e, srcA, dstA, etA, s, d, r);
        ssrc[t] = s; sdst[t] = d; srel[t] = r;
        sw[t] = 1.0f / (float)cnt[d * NREL + r];
    }
    __syncthreads();
    for (int e = 0; e < EB; ++e) {
        int s = ssrc[e];
        for (int idx = t; idx < F; idx += 256) {
            float v = in[(size_t)s * F + idx];
            xs[e][idx] = RELU_IN ? fmaxf(v, 0.f) : v;
        }
    }
    __syncthreads();
    int r0 = srel[0];
    bool uni = true;
    for (int e = 1; e < EB; ++e) uni = uni && (srel[e] == r0);
    if (uni) {
        const float* Wp = W + (size_t)r0 * F * HDIM;
        float acc[EB];
#pragma unroll
        for (int e = 0; e < EB; ++e) acc[e] = 0.f;
        for (int k = 0; k < F; ++k) {
            float wv = Wp[k * HDIM + t];
#pragma unroll
            for (int e = 0; e < EB; ++e) acc[e] += xs[e][k] * wv;
        }
        for (int e = 0; e < EB; ++e)
            atomicAdd(&out[(size_t)sdst[e] * HDIM + t], acc[e] * sw[e]);
    } else {
        for (int e = 0; e < EB; ++e) {
            const float* Wp = W + (size_t)srel[e] * F * HDIM;
            float a = 0.f;
            for (int k = 0; k < F; ++k) a += xs[e][k] * Wp[k * HDIM + t];
            atomicAdd(&out[(size_t)sdst[e] * HDIM + t], a * sw[e]);
        }
    }
}

// w = sigmoid(relu(h)·ws_w + ws_b); emb[batch[i]] += w * relu(h)
__global__ void pool_kernel(const float* __restrict__ h, const int* __restrict__ batch,
                            const float* __restrict__ wsw, const float* __restrict__ wsb,
                            float* __restrict__ emb) {
    int i = blockIdx.x;
    int t = threadIdx.x;
    float v = fmaxf(h[(size_t)i * HDIM + t], 0.f);
    float p = v * wsw[t];
    for (int off = 32; off >= 1; off >>= 1) p += __shfl_down(p, off, 64);
    __shared__ float red[4];
    __shared__ float ssig;
    if ((t & 63) == 0) red[t >> 6] = p;
    __syncthreads();
    if (t == 0) {
        float s = red[0] + red[1] + red[2] + red[3] + wsb[0];
        ssig = 1.0f / (1.0f + expf(-s));
    }
    __syncthreads();
    atomicAdd(&emb[(size_t)batch[i] * HDIM + t], ssig * v);
}

__global__ void mlp_kernel(const float* __restrict__ emb,
                           const float* __restrict__ m1w, const float* __restrict__ m1b,
                           const float* __restrict__ m2w, const float* __restrict__ m2b,
                           const float* __restrict__ m3w, const float* __restrict__ m3b,
                           const float* __restrict__ ow,  const float* __restrict__ ob,
                           float* __restrict__ out) {
    int g = blockIdx.x;
    int t = threadIdx.x; // 64 threads = 1 wave
    __shared__ float e[HDIM];
    __shared__ float z1[64], z2[64];
    for (int idx = t; idx < HDIM; idx += 64) e[idx] = emb[(size_t)g * HDIM + idx];
    __syncthreads();
    float a = m1b[t];
    for (int k = 0; k < HDIM; ++k) a += e[k] * m1w[k * 64 + t];
    z1[t] = fmaxf(a, 0.f);
    __syncthreads();
    a = m2b[t];
    for (int k = 0; k < 64; ++k) a += z1[k] * m2w[k * 64 + t];
    z2[t] = fmaxf(a, 0.f);
    __syncthreads();
    a = m3b[t];
    for (int k = 0; k < 64; ++k) a += z2[k] * m3w[k * 64 + t];
    float p = a * ow[t];
    for (int off = 32; off >= 1; off >>= 1) p += __shfl_down(p, off, 64);
    if (t == 0) out[g] = p + ob[0];
}

extern "C" void kernel_launch(void* const* d_in, const int* in_sizes, int n_in,
                              void* d_out, int out_size, void* d_ws, size_t ws_size,
                              hipStream_t stream) {
    const float* x     = (const float*)d_in[0];
    const int*   ei    = (const int*)d_in[1];
    const int*   src   = ei;
    const int*   dst   = ei + E_REAL;
    const int*   et    = (const int*)d_in[2];
    const int*   batch = (const int*)d_in[3];
    const float* W1    = (const float*)d_in[4];
    const float* root1 = (const float*)d_in[5];
    const float* b1    = (const float*)d_in[6];
    const float* W2    = (const float*)d_in[7];
    const float* root2 = (const float*)d_in[8];
    const float* b2    = (const float*)d_in[9];
    const float* wsw   = (const float*)d_in[10];
    const float* wsb   = (const float*)d_in[11];
    const float* m1w   = (const float*)d_in[12];
    const float* m1b   = (const float*)d_in[13];
    const float* m2w   = (const float*)d_in[14];
    const float* m2b   = (const float*)d_in[15];
    const float* m3w   = (const float*)d_in[16];
    const float* m3b   = (const float*)d_in[17];
    const float* ow    = (const float*)d_in[18];
    const float* ob    = (const float*)d_in[19];

    char* ws = (char*)d_ws;
    size_t off = 0;
    auto alloc = [&](size_t bytes) {
        void* p = ws + off;
        off = (off + bytes + 255) & ~(size_t)255;
        return p;
    };
    int*   cnt       = (int*)alloc((size_t)N_NODES * NREL * 4);   // 13.0 MB
    int*   blockHist = (int*)alloc((size_t)TOT_HIST * 4);         // 254 KB
    int*   baseArr   = (int*)alloc((size_t)TOT_HIST * 4);         // 254 KB
    int*   perm      = (int*)alloc((size_t)E_MEAN * 4);           // 1.0 MB
    float* h1        = (float*)alloc((size_t)N_NODES * HDIM * 4); // 51.2 MB
    float* h2        = (float*)alloc((size_t)N_NODES * HDIM * 4); // 51.2 MB
    float* emb       = (float*)alloc((size_t)NGRAPH * HDIM * 4);  // 1.6 MB

    hipMemsetAsync(cnt, 0, (size_t)N_NODES * NREL * 4, stream);
    hipMemsetAsync(emb, 0, (size_t)NGRAPH * HDIM * 4, stream);

    count_kernel<<<NB_E, 256, 0, stream>>>(src, dst, et, cnt, blockHist);
    scan_kernel<<<1, 1024, 0, stream>>>(blockHist, baseArr);
    scatter_sorted<<<NB_E, 256, 0, stream>>>(src, dst, et, baseArr, perm);

    // layer 1: h1 = x @ root1 + b1 ; += per-relation mean messages
    init_gemm<128, false><<<N_NODES / EB, 256, 0, stream>>>(x, root1, b1, h1);
    edge_gemm<128, false><<<E_MEAN / EB, 256, 0, stream>>>(x, W1, src, dst, et, perm, cnt, h1);
    // layer 2: input relu(h1)
    init_gemm<256, true><<<N_NODES / EB, 256, 0, stream>>>(h1, root2, b2, h2);
    edge_gemm<256, true><<<E_MEAN / EB, 256, 0, stream>>>(h1, W2, src, dst, et, perm, cnt, h2);

    pool_kernel<<<N_NODES, 256, 0, stream>>>(h2, batch, wsw, wsb, emb);
    mlp_kernel<<<NGRAPH, 64, 0, stream>>>(emb, m1w, m1b, m2w, m2b, m3w, m3b, ow, ob, (float*)d_out);
}

// Round 3
// 718.480 us; speedup vs baseline: 3.0327x; 1.8659x over previous
//
#include <hip/hip_runtime.h>
#include <math.h>

#define N_NODES 50000
#define E_REAL  200000
#define E_MEAN  250000   // real edges + self-loops (relation 0)
#define NREL    65
#define HDIM    256
#define NGRAPH  1600
#define NB_E    ((E_MEAN + 255) / 256)   // 977 blocks over edges
#define TOT_HIST (NREL * NB_E)           // 63505
#define MB      64                        // rows per MFMA block
#define MAX_PB  4096                      // upper bound on padded edge blocks

typedef __attribute__((ext_vector_type(8))) short short8;   // 8 bf16 (4 VGPRs)
typedef __attribute__((ext_vector_type(4))) float floatx4;  // MFMA C/D frag

__device__ __forceinline__ unsigned short f2bf(float f) {
    unsigned int u = __float_as_uint(f);
    unsigned int r = u + 0x7FFFu + ((u >> 16) & 1u);  // RNE
    return (unsigned short)(r >> 16);
}

// decode combined edge id: [0,E_REAL) real edges, [E_REAL,E_MEAN) self loops (rel 0)
__device__ __forceinline__ void decode_edge(int e, const int* __restrict__ src,
                                            const int* __restrict__ dst,
                                            const int* __restrict__ et,
                                            int& s, int& d, int& r) {
    if (e < E_REAL) { s = src[e]; d = dst[e]; r = et[e]; }
    else            { s = d = e - E_REAL; r = 0; }
}

__global__ void count_kernel(const int* __restrict__ src, const int* __restrict__ dst,
                             const int* __restrict__ et, int* __restrict__ cnt,
                             int* __restrict__ blockHist) {
    __shared__ int lhist[NREL];
    int t = threadIdx.x;
    if (t < NREL) lhist[t] = 0;
    __syncthreads();
    int e = blockIdx.x * blockDim.x + t;
    if (e < E_MEAN) {
        int s, d, r; decode_edge(e, src, dst, et, s, d, r);
        atomicAdd(&cnt[d * NREL + r], 1);
        atomicAdd(&lhist[r], 1);
    }
    __syncthreads();
    if (t < NREL) blockHist[t * NB_E + blockIdx.x] = lhist[t];
}

// exclusive scan of blockHist (relation-major) -> base; plus relation segment
// metadata and padded-block -> relation map for the MFMA edge kernel.
__global__ void scan_kernel(const int* __restrict__ in, int* __restrict__ out,
                            int* __restrict__ relStart, int* __restrict__ relTot,
                            int* __restrict__ pBlockStart, int* __restrict__ relOfBlock,
                            int* __restrict__ npb) {
    const int T = 1024;
    int t = threadIdx.x;
    const int per = (TOT_HIST + T - 1) / T;
    int start = t * per;
    int end = start + per; if (end > TOT_HIST) end = TOT_HIST;
    int s = 0;
    for (int i = start; i < end && i < TOT_HIST; ++i) s += in[i];
    __shared__ int sums[1024];
    sums[t] = s;
    __syncthreads();
    for (int off = 1; off < 1024; off <<= 1) {
        int v = (t >= off) ? sums[t - off] : 0;
        __syncthreads();
        sums[t] += v;
        __syncthreads();
    }
    int acc = (t == 0) ? 0 : sums[t - 1];
    for (int i = start; i < end && i < TOT_HIST; ++i) {
        int v = in[i];
        out[i] = acc;
        acc += v;
    }
    __syncthreads();
    // relation segment metadata
    __shared__ int sStart[NREL + 1];
    __shared__ int sPB[NREL + 1];
    if (t < NREL) sStart[t] = out[t * NB_E];
    if (t == 0) sStart[NREL] = E_MEAN;
    __syncthreads();
    if (t < NREL) {
        relStart[t] = sStart[t];
        relTot[t] = sStart[t + 1] - sStart[t];
    }
    if (t == 0) {
        int a2 = 0;
        for (int r = 0; r < NREL; ++r) {
            sPB[r] = a2;
            int tot = sStart[r + 1] - sStart[r];
            a2 += (tot + MB - 1) / MB;
        }
        sPB[NREL] = a2;
        npb[0] = a2;
    }
    __syncthreads();
    if (t < NREL) pBlockStart[t] = sPB[t];
    int NPB = sPB[NREL];
    for (int b = t; b < NPB; b += T) {
        int lo = 0, hi = NREL - 1;
        while (lo < hi) { int mid = (lo + hi + 1) >> 1; if (sPB[mid] <= b) lo = mid; else hi = mid - 1; }
        relOfBlock[b] = lo;
    }
}

__global__ void scatter_sorted(const int* __restrict__ src, const int* __restrict__ dst,
                               const int* __restrict__ et, const int* __restrict__ base,
                               int* __restrict__ perm) {
    __shared__ int lhist[NREL];
    int t = threadIdx.x;
    int b = blockIdx.x;
    if (t < NREL) lhist[t] = 0;
    __syncthreads();
    int e = b * 256 + t;
    if (e < E_MEAN) {
        int s, d, r; decode_edge(e, src, dst, et, s, d, r);
        int local = atomicAdd(&lhist[r], 1);
        perm[base[r * NB_E + b] + local] = e;
    }
}

// fp32 row-major -> bf16 (ushort) row-major, optional relu. One thread per 8 elems.
__global__ void cvt_rows(const float* __restrict__ in, unsigned short* __restrict__ out,
                         int nchunk, int relu) {
    int i = blockIdx.x * 256 + threadIdx.x;
    if (i >= nchunk) return;
    const float4* p = (const float4*)in + (size_t)i * 2;
    float4 a = p[0], b = p[1];
    float v[8] = {a.x, a.y, a.z, a.w, b.x, b.y, b.z, b.w};
    short8 o;
#pragma unroll
    for (int j = 0; j < 8; ++j) {
        float f = relu ? fmaxf(v[j], 0.f) : v[j];
        o[j] = (short)f2bf(f);
    }
    ((short8*)out)[i] = o;
}

// W fp32 [R][K][N] -> bf16 [R][N][K] (transposed per relation).
// One thread per output 16B chunk (8 k's for one n).
__global__ void cvt_wT(const float* __restrict__ W, unsigned short* __restrict__ out,
                       int R, int K, int N) {
    int kc8 = K / 8;
    int total = R * N * kc8;
    int i = blockIdx.x * 256 + threadIdx.x;
    if (i >= total) return;
    int kc = i % kc8;
    int tmp = i / kc8;
    int n = tmp % N;
    int r = tmp / N;
    const float* src = W + ((size_t)r * K + kc * 8) * N + n;
    short8 o;
#pragma unroll
    for (int j = 0; j < 8; ++j) o[j] = (short)f2bf(src[(size_t)j * N]);
    ((short8*)out)[i] = o;
}

// MFMA GEMM: 64 rows x 256 cols per block, 4 waves (each 64x64), K in {128,256}.
// EDGE: rows gathered via perm (relation-padded blocks), epilogue = weighted
//       atomic scatter to out[dst].
// !EDGE: dense rows, epilogue = out[row] = acc + bias.
template<int K, bool EDGE>
__global__ __launch_bounds__(256) void mfma_gemm(
    const unsigned short* __restrict__ A,   // [*][K] bf16 rows
    const unsigned short* __restrict__ B,   // [R][256][K] bf16 (transposed)
    const float* __restrict__ bias,
    float* __restrict__ out,                // [*][256] f32
    const int* __restrict__ perm, const int* __restrict__ srcA,
    const int* __restrict__ dstA, const int* __restrict__ etA,
    const int* __restrict__ cnt,
    const int* __restrict__ relOfBlock, const int* __restrict__ pBlockStart,
    const int* __restrict__ relStart, const int* __restrict__ relTot,
    const int* __restrict__ npb)
{
    constexpr int CH = K / 8;                 // 16B chunks per row
    __shared__ __align__(16) unsigned short As[MB * K];
    __shared__ int ssrc[MB];
    __shared__ int sdst[MB];
    __shared__ float sw[MB];
    int t = threadIdx.x;
    int b = blockIdx.x;
    int rel = 0, rowbase = 0;
    if (EDGE) {
        if (b >= npb[0]) return;
        rel = relOfBlock[b];
        int jb = b - pBlockStart[rel];
        int rs = relStart[rel];
        int nval = relTot[rel] - jb * MB; if (nval > MB) nval = MB;
        if (t < MB) {
            int s = 0, d = 0; float w = 0.f;
            if (t < nval) {
                int e = perm[rs + jb * MB + t];
                int rr; decode_edge(e, srcA, dstA, etA, s, d, rr);
                w = 1.0f / (float)cnt[d * NREL + rel];
            }
            ssrc[t] = s; sdst[t] = d; sw[t] = w;
        }
        __syncthreads();
    } else {
        rowbase = b * MB;
    }
    // stage A rows into LDS, XOR-swizzled 16B chunks (c ^= row&7) so the
    // ds_read_b128 A-fragment reads (16 lanes, same chunk, rows 0..15) spread banks
    for (int q = t; q < MB * CH; q += 256) {
        int row = q / CH, c = q % CH;
        int srow;
        if (EDGE) srow = ssrc[row];
        else { srow = rowbase + row; if (srow >= N_NODES) srow = N_NODES - 1; }
        uint4 v = *(const uint4*)(A + (size_t)srow * K + c * 8);
        *(uint4*)((char*)As + row * (K * 2) + ((c ^ (row & 7)) * 16)) = v;
    }
    __syncthreads();

    int wave = t >> 6, lane = t & 63;
    int n0 = wave * 64;
    int lrow = lane & 15;     // A row / B col within fragment
    int lk = lane >> 4;       // k-subgroup 0..3
    floatx4 acc[4][4];
#pragma unroll
    for (int mf = 0; mf < 4; ++mf)
#pragma unroll
        for (int nf = 0; nf < 4; ++nf) acc[mf][nf] = (floatx4)0.f;

    const unsigned short* Bp = B + ((size_t)rel * HDIM + n0) * K;
#pragma unroll
    for (int ks = 0; ks < K / 32; ++ks) {
        short8 a[4], bb[4];
#pragma unroll
        for (int mf = 0; mf < 4; ++mf) {
            int row = mf * 16 + lrow;
            int c = (ks * 4 + lk) ^ (row & 7);
            a[mf] = *(const short8*)((const char*)As + row * (K * 2) + c * 16);
        }
#pragma unroll
        for (int nf = 0; nf < 4; ++nf)
            bb[nf] = *(const short8*)(Bp + (size_t)(nf * 16 + lrow) * K + ks * 32 + lk * 8);
#pragma unroll
        for (int mf = 0; mf < 4; ++mf)
#pragma unroll
            for (int nf = 0; nf < 4; ++nf)
                acc[mf][nf] = __builtin_amdgcn_mfma_f32_16x16x32_bf16(a[mf], bb[nf], acc[mf][nf], 0, 0, 0);
    }

    // C/D layout: col = lane&15, row = (lane>>4)*4 + reg
    if (EDGE) {
#pragma unroll
        for (int mf = 0; mf < 4; ++mf) {
            int mbase = mf * 16 + lk * 4;
#pragma unroll
            for (int i = 0; i < 4; ++i) {
                int mm = mbase + i;
                float w = sw[mm];
                if (w != 0.f) {
                    int drow = sdst[mm];
#pragma unroll
                    for (int nf = 0; nf < 4; ++nf) {
                        int col = n0 + nf * 16 + lrow;
                        atomicAdd(&out[(size_t)drow * HDIM + col], acc[mf][nf][i] * w);
                    }
                }
            }
        }
    } else {
        float bv[4];
#pragma unroll
        for (int nf = 0; nf < 4; ++nf) bv[nf] = bias[n0 + nf * 16 + lrow];
#pragma unroll
        for (int mf = 0; mf < 4; ++mf) {
            int mbase = mf * 16 + lk * 4;
#pragma unroll
            for (int i = 0; i < 4; ++i) {
                int mm = rowbase + mbase + i;
                if (mm < N_NODES) {
#pragma unroll
                    for (int nf = 0; nf < 4; ++nf) {
                        int col = n0 + nf * 16 + lrow;
                        out[(size_t)mm * HDIM + col] = acc[mf][nf][i] + bv[nf];
                    }
                }
            }
        }
    }
}

// w = sigmoid(relu(h)·ws_w + ws_b); emb[batch[i]] += w * relu(h)
__global__ void pool_kernel(const float* __restrict__ h, const int* __restrict__ batch,
                            const float* __restrict__ wsw, const float* __restrict__ wsb,
                            float* __restrict__ emb) {
    int i = blockIdx.x;
    int t = threadIdx.x;
    float v = fmaxf(h[(size_t)i * HDIM + t], 0.f);
    float p = v * wsw[t];
    for (int off = 32; off >= 1; off >>= 1) p += __shfl_down(p, off, 64);
    __shared__ float red[4];
    __shared__ float ssig;
    if ((t & 63) == 0) red[t >> 6] = p;
    __syncthreads();
    if (t == 0) {
        float s = red[0] + red[1] + red[2] + red[3] + wsb[0];
        ssig = 1.0f / (1.0f + expf(-s));
    }
    __syncthreads();
    atomicAdd(&emb[(size_t)batch[i] * HDIM + t], ssig * v);
}

__global__ void mlp_kernel(const float* __restrict__ emb,
                           const float* __restrict__ m1w, const float* __restrict__ m1b,
                           const float* __restrict__ m2w, const float* __restrict__ m2b,
                           const float* __restrict__ m3w, const float* __restrict__ m3b,
                           const float* __restrict__ ow,  const float* __restrict__ ob,
                           float* __restrict__ out) {
    int g = blockIdx.x;
    int t = threadIdx.x; // 64 threads = 1 wave
    __shared__ float e[HDIM];
    __shared__ float z1[64], z2[64];
    for (int idx = t; idx < HDIM; idx += 64) e[idx] = emb[(size_t)g * HDIM + idx];
    __syncthreads();
    float a = m1b[t];
    for (int k = 0; k < HDIM; ++k) a += e[k] * m1w[k * 64 + t];
    z1[t] = fmaxf(a, 0.f);
    __syncthreads();
    a = m2b[t];
    for (int k = 0; k < 64; ++k) a += z1[k] * m2w[k * 64 + t];
    z2[t] = fmaxf(a, 0.f);
    __syncthreads();
    a = m3b[t];
    for (int k = 0; k < 64; ++k) a += z2[k] * m3w[k * 64 + t];
    float p = a * ow[t];
    for (int off = 32; off >= 1; off >>= 1) p += __shfl_down(p, off, 64);
    if (t == 0) out[g] = p + ob[0];
}

extern "C" void kernel_launch(void* const* d_in, const int* in_sizes, int n_in,
                              void* d_out, int out_size, void* d_ws, size_t ws_size,
                              hipStream_t stream) {
    const float* x     = (const float*)d_in[0];
    const int*   ei    = (const int*)d_in[1];
    const int*   src   = ei;
    const int*   dst   = ei + E_REAL;
    const int*   et    = (const int*)d_in[2];
    const int*   batch = (const int*)d_in[3];
    const float* W1    = (const float*)d_in[4];
    const float* root1 = (const float*)d_in[5];
    const float* b1    = (const float*)d_in[6];
    const float* W2    = (const float*)d_in[7];
    const float* root2 = (const float*)d_in[8];
    const float* b2    = (const float*)d_in[9];
    const float* wsw   = (const float*)d_in[10];
    const float* wsb   = (const float*)d_in[11];
    const float* m1w   = (const float*)d_in[12];
    const float* m1b   = (const float*)d_in[13];
    const float* m2w   = (const float*)d_in[14];
    const float* m2b   = (const float*)d_in[15];
    const float* m3w   = (const float*)d_in[16];
    const float* m3b   = (const float*)d_in[17];
    const float* ow    = (const float*)d_in[18];
    const float* ob    = (const float*)d_in[19];

    char* ws = (char*)d_ws;
    size_t off = 0;
    auto alloc = [&](size_t bytes) {
        void* p = ws + off;
        off = (off + bytes + 255) & ~(size_t)255;
        return p;
    };
    int*   cnt       = (int*)alloc((size_t)N_NODES * NREL * 4);     // 13.0 MB
    int*   blockHist = (int*)alloc((size_t)TOT_HIST * 4);
    int*   baseArr   = (int*)alloc((size_t)TOT_HIST * 4);
    int*   perm      = (int*)alloc((size_t)E_MEAN * 4);             // 1.0 MB
    int*   relStartA = (int*)alloc(NREL * 4);
    int*   relTotA   = (int*)alloc(NREL * 4);
    int*   pbStartA  = (int*)alloc(NREL * 4);
    int*   relOfBlk  = (int*)alloc(MAX_PB * 4);
    int*   npb       = (int*)alloc(4);
    unsigned short* xb  = (unsigned short*)alloc((size_t)N_NODES * 128 * 2);   // 12.8 MB
    unsigned short* w1b = (unsigned short*)alloc((size_t)NREL * 256 * 128 * 2); // 4.3 MB
    unsigned short* w2b = (unsigned short*)alloc((size_t)NREL * 256 * 256 * 2); // 8.5 MB
    unsigned short* r1b = (unsigned short*)alloc((size_t)256 * 128 * 2);
    unsigned short* r2b = (unsigned short*)alloc((size_t)256 * 256 * 2);
    float* h   = (float*)alloc((size_t)N_NODES * HDIM * 4);         // 51.2 MB (h1 then h2)
    unsigned short* h1b = (unsigned short*)alloc((size_t)N_NODES * HDIM * 2);  // 25.6 MB
    float* emb = (float*)alloc((size_t)NGRAPH * HDIM * 4);          // 1.6 MB

    hipMemsetAsync(cnt, 0, (size_t)N_NODES * NREL * 4, stream);
    hipMemsetAsync(emb, 0, (size_t)NGRAPH * HDIM * 4, stream);

    count_kernel<<<NB_E, 256, 0, stream>>>(src, dst, et, cnt, blockHist);
    scan_kernel<<<1, 1024, 0, stream>>>(blockHist, baseArr, relStartA, relTotA,
                                        pbStartA, relOfBlk, npb);
    scatter_sorted<<<NB_E, 256, 0, stream>>>(src, dst, et, baseArr, perm);

    // bf16 conversions
    cvt_rows<<<(N_NODES * 128 / 8 + 255) / 256, 256, 0, stream>>>(x, xb, N_NODES * 128 / 8, 0);
    cvt_wT<<<(NREL * 256 * 16 + 255) / 256, 256, 0, stream>>>(W1, w1b, NREL, 128, 256);
    cvt_wT<<<(NREL * 256 * 32 + 255) / 256, 256, 0, stream>>>(W2, w2b, NREL, 256, 256);
    cvt_wT<<<(256 * 16 + 255) / 256, 256, 0, stream>>>(root1, r1b, 1, 128, 256);
    cvt_wT<<<(256 * 32 + 255) / 256, 256, 0, stream>>>(root2, r2b, 1, 256, 256);

    const int grid_init = (N_NODES + MB - 1) / MB;  // 782
    // layer 1
    mfma_gemm<128, false><<<grid_init, 256, 0, stream>>>(xb, r1b, b1, h,
        nullptr, nullptr, nullptr, nullptr, nullptr, nullptr, nullptr, nullptr, nullptr, nullptr);
    mfma_gemm<128, true><<<MAX_PB, 256, 0, stream>>>(xb, w1b, nullptr, h,
        perm, src, dst, et, cnt, relOfBlk, pbStartA, relStartA, relTotA, npb);
    cvt_rows<<<(N_NODES * HDIM / 8 + 255) / 256, 256, 0, stream>>>(h, h1b, N_NODES * HDIM / 8, 1);
    // layer 2 (h reused as h2; h1 f32 dead after conversion)
    mfma_gemm<256, false><<<grid_init, 256, 0, stream>>>(h1b, r2b, b2, h,
        nullptr, nullptr, nullptr, nullptr, nullptr, nullptr, nullptr, nullptr, nullptr, nullptr);
    mfma_gemm<256, true><<<MAX_PB, 256, 0, stream>>>(h1b, w2b, nullptr, h,
        perm, src, dst, et, cnt, relOfBlk, pbStartA, relStartA, relTotA, npb);

    pool_kernel<<<N_NODES, 256, 0, stream>>>(h, batch, wsw, wsb, emb);
    mlp_kernel<<<NGRAPH, 64, 0, stream>>>(emb, m1w, m1b, m2w, m2b, m3w, m3b, ow, ob, (float*)d_out);
}

// Round 4
// 656.333 us; speedup vs baseline: 3.3199x; 1.0947x over previous
//
#include <hip/hip_runtime.h>
#include <math.h>

#define N_NODES 50000
#define E_REAL  200000
#define E_MEAN  250000   // real edges + self-loops (relation 0)
#define NREL    65
#define HDIM    256
#define NGRAPH  1600
#define NB_E    ((E_MEAN + 255) / 256)   // 977 blocks over edges
#define TOT_HIST (NREL * NB_E)           // 63505
#define MB      64                        // rows per MFMA block
#define MAX_PB  4096                      // upper bound on padded edge blocks

typedef __attribute__((ext_vector_type(8))) short short8;   // 8 bf16 (4 VGPRs)
typedef __attribute__((ext_vector_type(4))) float floatx4;  // MFMA C/D frag

__device__ __forceinline__ unsigned short f2bf(float f) {
    unsigned int u = __float_as_uint(f);
    unsigned int r = u + 0x7FFFu + ((u >> 16) & 1u);  // RNE
    return (unsigned short)(r >> 16);
}
__device__ __forceinline__ float bf2f(unsigned short u) {
    return __uint_as_float(((unsigned int)u) << 16);
}

// decode combined edge id: [0,E_REAL) real edges, [E_REAL,E_MEAN) self loops (rel 0)
__device__ __forceinline__ void decode_edge(int e, const int* __restrict__ src,
                                            const int* __restrict__ dst,
                                            const int* __restrict__ et,
                                            int& s, int& d, int& r) {
    if (e < E_REAL) { s = src[e]; d = dst[e]; r = et[e]; }
    else            { s = d = e - E_REAL; r = 0; }
}

__global__ void count_kernel(const int* __restrict__ src, const int* __restrict__ dst,
                             const int* __restrict__ et, int* __restrict__ cnt,
                             int* __restrict__ blockHist, int* __restrict__ cntD) {
    __shared__ int lhist[NREL];
    int t = threadIdx.x;
    if (t < NREL) lhist[t] = 0;
    __syncthreads();
    int e = blockIdx.x * blockDim.x + t;
    if (e < E_MEAN) {
        int s, d, r; decode_edge(e, src, dst, et, s, d, r);
        atomicAdd(&cnt[d * NREL + r], 1);
        atomicAdd(&cntD[d], 1);
        atomicAdd(&lhist[r], 1);
    }
    __syncthreads();
    if (t < NREL) blockHist[t * NB_E + blockIdx.x] = lhist[t];
}

// exclusive scan of blockHist (relation-major) -> base; relation segment metadata;
// padded-block -> relation map.
__global__ void scan_kernel(const int* __restrict__ in, int* __restrict__ out,
                            int* __restrict__ relStart, int* __restrict__ relTot,
                            int* __restrict__ pBlockStart, int* __restrict__ relOfBlock,
                            int* __restrict__ npb) {
    const int T = 1024;
    int t = threadIdx.x;
    const int per = (TOT_HIST + T - 1) / T;
    int start = t * per;
    int end = start + per; if (end > TOT_HIST) end = TOT_HIST;
    int s = 0;
    for (int i = start; i < end && i < TOT_HIST; ++i) s += in[i];
    __shared__ int sums[1024];
    sums[t] = s;
    __syncthreads();
    for (int off = 1; off < 1024; off <<= 1) {
        int v = (t >= off) ? sums[t - off] : 0;
        __syncthreads();
        sums[t] += v;
        __syncthreads();
    }
    int acc = (t == 0) ? 0 : sums[t - 1];
    for (int i = start; i < end && i < TOT_HIST; ++i) {
        int v = in[i];
        out[i] = acc;
        acc += v;
    }
    __syncthreads();
    __shared__ int sStart[NREL + 1];
    __shared__ int sPB[NREL + 1];
    if (t < NREL) sStart[t] = out[t * NB_E];
    if (t == 0) sStart[NREL] = E_MEAN;
    __syncthreads();
    if (t < NREL) {
        relStart[t] = sStart[t];
        relTot[t] = sStart[t + 1] - sStart[t];
    }
    if (t == 0) {
        int a2 = 0;
        for (int r = 0; r < NREL; ++r) {
            sPB[r] = a2;
            int tot = sStart[r + 1] - sStart[r];
            a2 += (tot + MB - 1) / MB;
        }
        sPB[NREL] = a2;
        npb[0] = a2;
    }
    __syncthreads();
    if (t < NREL) pBlockStart[t] = sPB[t];
    int NPB = sPB[NREL];
    for (int b = t; b < NPB; b += T) {
        int lo = 0, hi = NREL - 1;
        while (lo < hi) { int mid = (lo + hi + 1) >> 1; if (sPB[mid] <= b) lo = mid; else hi = mid - 1; }
        relOfBlock[b] = lo;
    }
}

// exclusive scan of per-dst counts -> startD, cursorD
__global__ void scan_dst(const int* __restrict__ cntD, int* __restrict__ startD,
                         int* __restrict__ cursorD) {
    const int T = 1024;
    int t = threadIdx.x;
    const int per = (N_NODES + T - 1) / T;  // 49
    int start = t * per;
    int end = start + per; if (end > N_NODES) end = N_NODES;
    int s = 0;
    for (int i = start; i < end; ++i) s += cntD[i];
    __shared__ int sums[1024];
    sums[t] = s;
    __syncthreads();
    for (int off = 1; off < 1024; off <<= 1) {
        int v = (t >= off) ? sums[t - off] : 0;
        __syncthreads();
        sums[t] += v;
        __syncthreads();
    }
    int acc = (t == 0) ? 0 : sums[t - 1];
    for (int i = start; i < end; ++i) {
        int v = cntD[i];
        startD[i] = acc;
        cursorD[i] = acc;
        acc += v;
    }
}

// counting-sort scatter by relation; also build dst-sorted slot -> rel-sorted pos
__global__ void scatter_sorted(const int* __restrict__ src, const int* __restrict__ dst,
                               const int* __restrict__ et, const int* __restrict__ base,
                               int* __restrict__ perm, int* __restrict__ cursorD,
                               int* __restrict__ pofq) {
    __shared__ int lhist[NREL];
    int t = threadIdx.x;
    int b = blockIdx.x;
    if (t < NREL) lhist[t] = 0;
    __syncthreads();
    int e = b * 256 + t;
    if (e < E_MEAN) {
        int s, d, r; decode_edge(e, src, dst, et, s, d, r);
        int local = atomicAdd(&lhist[r], 1);
        int p = base[r * NB_E + b] + local;
        perm[p] = e;
        int q = atomicAdd(&cursorD[d], 1);
        pofq[q] = p;
    }
}

// fp32 row-major -> bf16 row-major, optional relu. One thread per 8 elems.
__global__ void cvt_rows(const float* __restrict__ in, unsigned short* __restrict__ out,
                         int nchunk, int relu) {
    int i = blockIdx.x * 256 + threadIdx.x;
    if (i >= nchunk) return;
    const float4* p = (const float4*)in + (size_t)i * 2;
    float4 a = p[0], b = p[1];
    float v[8] = {a.x, a.y, a.z, a.w, b.x, b.y, b.z, b.w};
    short8 o;
#pragma unroll
    for (int j = 0; j < 8; ++j) {
        float f = relu ? fmaxf(v[j], 0.f) : v[j];
        o[j] = (short)f2bf(f);
    }
    ((short8*)out)[i] = o;
}

// W fp32 [R][K][N] -> bf16 [R][N][K]
__global__ void cvt_wT(const float* __restrict__ W, unsigned short* __restrict__ out,
                       int R, int K, int N) {
    int kc8 = K / 8;
    int total = R * N * kc8;
    int i = blockIdx.x * 256 + threadIdx.x;
    if (i >= total) return;
    int kc = i % kc8;
    int tmp = i / kc8;
    int n = tmp % N;
    int r = tmp / N;
    const float* src = W + ((size_t)r * K + kc * 8) * N + n;
    short8 o;
#pragma unroll
    for (int j = 0; j < 8; ++j) o[j] = (short)f2bf(src[(size_t)j * N]);
    ((short8*)out)[i] = o;
}

// MFMA GEMM: 64 rows x 256 cols per block, 4 waves (each 64x64).
// MODE 0: INIT dense rows -> fp32 out + bias (fallback)
// MODE 1: EDGE gathered rows -> weighted fp32 atomic scatter (fallback)
// MODE 2: INIT dense rows -> bf16 out + bias (via LDS repack, coalesced)
// MODE 3: EDGE gathered rows -> weighted bf16 msg rows (via LDS repack)
template<int K, int MODE>
__global__ __launch_bounds__(256) void mfma_gemm(
    const unsigned short* __restrict__ A,   // [*][K] bf16 rows
    const unsigned short* __restrict__ B,   // [R][256][K] bf16 (transposed)
    const float* __restrict__ bias,
    float* __restrict__ outF,
    unsigned short* __restrict__ outB,
    const int* __restrict__ perm, const int* __restrict__ srcA,
    const int* __restrict__ dstA, const int* __restrict__ etA,
    const int* __restrict__ cnt,
    const int* __restrict__ relOfBlock, const int* __restrict__ pBlockStart,
    const int* __restrict__ relStart, const int* __restrict__ relTot,
    const int* __restrict__ npb)
{
    constexpr bool EDGE = (MODE == 1 || MODE == 3);
    constexpr int CH = K / 8;                 // 16B chunks per row
    __shared__ __align__(16) unsigned short lds[MB * HDIM];  // A staging (MB*K) / repack (MB*256)
    __shared__ int ssrc[MB];
    __shared__ int sdst[MB];
    __shared__ float sw[MB];
    int t = threadIdx.x;
    int b = blockIdx.x;
    int rel = 0, rowbase = 0, jb = 0, rs = 0, nval = MB;
    if constexpr (EDGE) {
        if (b >= npb[0]) return;
        rel = relOfBlock[b];
        jb = b - pBlockStart[rel];
        rs = relStart[rel];
        nval = relTot[rel] - jb * MB; if (nval > MB) nval = MB;
        if (t < MB) {
            int s = 0, d = 0; float w = 0.f;
            if (t < nval) {
                int e = perm[rs + jb * MB + t];
                int rr; decode_edge(e, srcA, dstA, etA, s, d, rr);
                w = 1.0f / (float)cnt[d * NREL + rel];
            }
            ssrc[t] = s; sdst[t] = d; sw[t] = w;
        }
        __syncthreads();
    } else {
        rowbase = b * MB;
    }
    // stage A rows into LDS, XOR-swizzled 16B chunks (c ^= row&7)
    for (int q = t; q < MB * CH; q += 256) {
        int row = q / CH, c = q % CH;
        int srow;
        if constexpr (EDGE) srow = ssrc[row];
        else { srow = rowbase + row; if (srow >= N_NODES) srow = N_NODES - 1; }
        uint4 v = *(const uint4*)(A + (size_t)srow * K + c * 8);
        *(uint4*)((char*)lds + row * (K * 2) + ((c ^ (row & 7)) * 16)) = v;
    }
    __syncthreads();

    int wave = t >> 6, lane = t & 63;
    int n0 = wave * 64;
    int lrow = lane & 15;
    int lk = lane >> 4;
    floatx4 acc[4][4];
#pragma unroll
    for (int mf = 0; mf < 4; ++mf)
#pragma unroll
        for (int nf = 0; nf < 4; ++nf) acc[mf][nf] = (floatx4)0.f;

    const unsigned short* Bp = B + ((size_t)rel * HDIM + n0) * K;
    constexpr int KS = K / 32;
    short8 b_cur[4], b_nxt[4];
#pragma unroll
    for (int nf = 0; nf < 4; ++nf)
        b_cur[nf] = *(const short8*)(Bp + (size_t)(nf * 16 + lrow) * K + lk * 8);
#pragma unroll
    for (int ks = 0; ks < KS; ++ks) {
        short8 a[4];
#pragma unroll
        for (int mf = 0; mf < 4; ++mf) {
            int row = mf * 16 + lrow;
            int c = (ks * 4 + lk) ^ (row & 7);
            a[mf] = *(const short8*)((const char*)lds + row * (K * 2) + c * 16);
        }
        if (ks + 1 < KS) {
#pragma unroll
            for (int nf = 0; nf < 4; ++nf)
                b_nxt[nf] = *(const short8*)(Bp + (size_t)(nf * 16 + lrow) * K + (ks + 1) * 32 + lk * 8);
        }
#pragma unroll
        for (int mf = 0; mf < 4; ++mf)
#pragma unroll
            for (int nf = 0; nf < 4; ++nf)
                acc[mf][nf] = __builtin_amdgcn_mfma_f32_16x16x32_bf16(a[mf], b_cur[nf], acc[mf][nf], 0, 0, 0);
#pragma unroll
        for (int nf = 0; nf < 4; ++nf) b_cur[nf] = b_nxt[nf];
    }

    // C/D layout: col = lane&15, row = (lane>>4)*4 + reg
    if constexpr (MODE == 1) {
#pragma unroll
        for (int mf = 0; mf < 4; ++mf) {
            int mbase = mf * 16 + lk * 4;
#pragma unroll
            for (int i = 0; i < 4; ++i) {
                int mm = mbase + i;
                float w = sw[mm];
                if (w != 0.f) {
                    int drow = sdst[mm];
#pragma unroll
                    for (int nf = 0; nf < 4; ++nf) {
                        int col = n0 + nf * 16 + lrow;
                        atomicAdd(&outF[(size_t)drow * HDIM + col], acc[mf][nf][i] * w);
                    }
                }
            }
        }
    } else if constexpr (MODE == 0) {
        float bv[4];
#pragma unroll
        for (int nf = 0; nf < 4; ++nf) bv[nf] = bias[n0 + nf * 16 + lrow];
#pragma unroll
        for (int mf = 0; mf < 4; ++mf) {
            int mbase = mf * 16 + lk * 4;
#pragma unroll
            for (int i = 0; i < 4; ++i) {
                int mm = rowbase + mbase + i;
                if (mm < N_NODES) {
#pragma unroll
                    for (int nf = 0; nf < 4; ++nf) {
                        int col = n0 + nf * 16 + lrow;
                        outF[(size_t)mm * HDIM + col] = acc[mf][nf][i] + bv[nf];
                    }
                }
            }
        }
    } else {
        // MODE 2 / 3: repack to bf16 in LDS, then coalesced row stores
        float bv[4];
        if constexpr (MODE == 2) {
#pragma unroll
            for (int nf = 0; nf < 4; ++nf) bv[nf] = bias[n0 + nf * 16 + lrow];
        }
        __syncthreads();  // A staging reads done; reuse lds
#pragma unroll
        for (int mf = 0; mf < 4; ++mf) {
            int mbase = mf * 16 + lk * 4;
#pragma unroll
            for (int i = 0; i < 4; ++i) {
                int row = mbase + i;
                float w = (MODE == 3) ? sw[row] : 0.f;
#pragma unroll
                for (int nf = 0; nf < 4; ++nf) {
                    int col = n0 + nf * 16 + lrow;
                    float v = acc[mf][nf][i];
                    if constexpr (MODE == 3) v *= w;
                    else v += bv[nf];
                    lds[row * HDIM + col] = f2bf(v);
                }
            }
        }
        __syncthreads();
        int limit;
        size_t rb;
        if constexpr (MODE == 3) { limit = nval; rb = (size_t)rs + (size_t)jb * MB; }
        else { limit = N_NODES - rowbase; if (limit > MB) limit = MB; rb = (size_t)rowbase; }
        for (int q = t; q < limit * 32; q += 256) {
            int row = q >> 5, c = q & 31;
            *(uint4*)(outB + (rb + row) * HDIM + c * 8) = *(const uint4*)(lds + row * HDIM + c * 8);
        }
    }
}

// gather-reduce messages per dst. FUSE_POOL=0: h1b = relu(init+sum) bf16.
// FUSE_POOL=1: v = relu(init+sum); pool -> emb atomics (h2 never materialized).
template<int FUSE_POOL>
__global__ void reduce_kernel(const unsigned short* __restrict__ hinit,
                              const unsigned short* __restrict__ msg,
                              const int* __restrict__ pofq, const int* __restrict__ startD,
                              const int* __restrict__ cntD,
                              unsigned short* __restrict__ h1b,
                              const int* __restrict__ batch, const float* __restrict__ wsw,
                              const float* __restrict__ wsb, float* __restrict__ emb) {
    int t = threadIdx.x;
    int d0 = blockIdx.x * 16;
    __shared__ float red[4];
    __shared__ float ssig;
    for (int j = 0; j < 16; ++j) {
        int d = d0 + j;
        int s0 = startD[d], n = cntD[d];
        float acc = 0.f;
        for (int q = 0; q < n; ++q) {
            int p = pofq[s0 + q];
            acc += bf2f(msg[(size_t)p * HDIM + t]);
        }
        float v = bf2f(hinit[(size_t)d * HDIM + t]) + acc;
        v = fmaxf(v, 0.f);
        if constexpr (FUSE_POOL == 0) {
            h1b[(size_t)d * HDIM + t] = f2bf(v);
        } else {
            float p = v * wsw[t];
            for (int off = 32; off >= 1; off >>= 1) p += __shfl_down(p, off, 64);
            if ((t & 63) == 0) red[t >> 6] = p;
            __syncthreads();
            if (t == 0) {
                float s = red[0] + red[1] + red[2] + red[3] + wsb[0];
                ssig = 1.0f / (1.0f + expf(-s));
            }
            __syncthreads();
            atomicAdd(&emb[(size_t)batch[d] * HDIM + t], ssig * v);
            __syncthreads();
        }
    }
}

// fallback pool (fp32 h input)
__global__ void pool_kernel(const float* __restrict__ h, const int* __restrict__ batch,
                            const float* __restrict__ wsw, const float* __restrict__ wsb,
                            float* __restrict__ emb) {
    int i = blockIdx.x;
    int t = threadIdx.x;
    float v = fmaxf(h[(size_t)i * HDIM + t], 0.f);
    float p = v * wsw[t];
    for (int off = 32; off >= 1; off >>= 1) p += __shfl_down(p, off, 64);
    __shared__ float red[4];
    __shared__ float ssig;
    if ((t & 63) == 0) red[t >> 6] = p;
    __syncthreads();
    if (t == 0) {
        float s = red[0] + red[1] + red[2] + red[3] + wsb[0];
        ssig = 1.0f / (1.0f + expf(-s));
    }
    __syncthreads();
    atomicAdd(&emb[(size_t)batch[i] * HDIM + t], ssig * v);
}

__global__ void mlp_kernel(const float* __restrict__ emb,
                           const float* __restrict__ m1w, const float* __restrict__ m1b,
                           const float* __restrict__ m2w, const float* __restrict__ m2b,
                           const float* __restrict__ m3w, const float* __restrict__ m3b,
                           const float* __restrict__ ow,  const float* __restrict__ ob,
                           float* __restrict__ out) {
    int g = blockIdx.x;
    int t = threadIdx.x; // 64 threads = 1 wave
    __shared__ float e[HDIM];
    __shared__ float z1[64], z2[64];
    for (int idx = t; idx < HDIM; idx += 64) e[idx] = emb[(size_t)g * HDIM + idx];
    __syncthreads();
    float a = m1b[t];
    for (int k = 0; k < HDIM; ++k) a += e[k] * m1w[k * 64 + t];
    z1[t] = fmaxf(a, 0.f);
    __syncthreads();
    a = m2b[t];
    for (int k = 0; k < 64; ++k) a += z1[k] * m2w[k * 64 + t];
    z2[t] = fmaxf(a, 0.f);
    __syncthreads();
    a = m3b[t];
    for (int k = 0; k < 64; ++k) a += z2[k] * m3w[k * 64 + t];
    float p = a * ow[t];
    for (int off = 32; off >= 1; off >>= 1) p += __shfl_down(p, off, 64);
    if (t == 0) out[g] = p + ob[0];
}

extern "C" void kernel_launch(void* const* d_in, const int* in_sizes, int n_in,
                              void* d_out, int out_size, void* d_ws, size_t ws_size,
                              hipStream_t stream) {
    const float* x     = (const float*)d_in[0];
    const int*   ei    = (const int*)d_in[1];
    const int*   src   = ei;
    const int*   dst   = ei + E_REAL;
    const int*   et    = (const int*)d_in[2];
    const int*   batch = (const int*)d_in[3];
    const float* W1    = (const float*)d_in[4];
    const float* root1 = (const float*)d_in[5];
    const float* b1    = (const float*)d_in[6];
    const float* W2    = (const float*)d_in[7];
    const float* root2 = (const float*)d_in[8];
    const float* b2    = (const float*)d_in[9];
    const float* wsw   = (const float*)d_in[10];
    const float* wsb   = (const float*)d_in[11];
    const float* m1w   = (const float*)d_in[12];
    const float* m1b   = (const float*)d_in[13];
    const float* m2w   = (const float*)d_in[14];
    const float* m2b   = (const float*)d_in[15];
    const float* m3w   = (const float*)d_in[16];
    const float* m3b   = (const float*)d_in[17];
    const float* ow    = (const float*)d_in[18];
    const float* ob    = (const float*)d_in[19];

    char* ws = (char*)d_ws;
    size_t off = 0;
    auto alloc = [&](size_t bytes) {
        void* p = ws + off;
        off = (off + bytes + 255) & ~(size_t)255;
        return p;
    };
    // common buffers
    int*   cnt       = (int*)alloc((size_t)N_NODES * NREL * 4);     // 13.0 MB
    int*   blockHist = (int*)alloc((size_t)TOT_HIST * 4);
    int*   baseArr   = (int*)alloc((size_t)TOT_HIST * 4);
    int*   perm      = (int*)alloc((size_t)E_MEAN * 4);             // 1.0 MB
    int*   relStartA = (int*)alloc(NREL * 4);
    int*   relTotA   = (int*)alloc(NREL * 4);
    int*   pbStartA  = (int*)alloc(NREL * 4);
    int*   relOfBlk  = (int*)alloc(MAX_PB * 4);
    int*   npb       = (int*)alloc(4);
    unsigned short* xb  = (unsigned short*)alloc((size_t)N_NODES * 128 * 2);    // 12.8 MB
    unsigned short* w1b = (unsigned short*)alloc((size_t)NREL * 256 * 128 * 2); // 4.3 MB
    unsigned short* w2b = (unsigned short*)alloc((size_t)NREL * 256 * 256 * 2); // 8.5 MB
    unsigned short* r1b = (unsigned short*)alloc((size_t)256 * 128 * 2);
    unsigned short* r2b = (unsigned short*)alloc((size_t)256 * 256 * 2);
    unsigned short* h1b = (unsigned short*)alloc((size_t)N_NODES * HDIM * 2);   // 25.6 MB
    float* emb = (float*)alloc((size_t)NGRAPH * HDIM * 4);                       // 1.6 MB
    size_t off_common = off;

    // fast-path extras
    unsigned short* hinit = (unsigned short*)alloc((size_t)N_NODES * HDIM * 2); // 25.6 MB
    unsigned short* msg   = (unsigned short*)alloc((size_t)E_MEAN * HDIM * 2);  // 128 MB
    int* pofq    = (int*)alloc((size_t)E_MEAN * 4);
    int* cntD    = (int*)alloc((size_t)N_NODES * 4);
    int* startD  = (int*)alloc((size_t)N_NODES * 4);
    int* cursorD = (int*)alloc((size_t)N_NODES * 4);
    size_t need_fast = off;

    float* hf = nullptr;
    bool fast = (ws_size >= need_fast);
    if (!fast) {
        // fallback layout: round-3 proven footprint; dst structures alias hf
        off = off_common;
        hf = (float*)alloc((size_t)N_NODES * HDIM * 4);  // 51.2 MB
        char* hh = (char*)hf;
        pofq    = (int*)hh;                                 hh += (size_t)E_MEAN * 4;
        cntD    = (int*)hh;                                 hh += (size_t)N_NODES * 4;
        startD  = (int*)hh;                                 hh += (size_t)N_NODES * 4;
        cursorD = (int*)hh;
        hinit = h1b;  // unused sink
        msg = h1b;    // unused sink
    }

    hipMemsetAsync(cnt, 0, (size_t)N_NODES * NREL * 4, stream);
    hipMemsetAsync(cntD, 0, (size_t)N_NODES * 4, stream);
    hipMemsetAsync(emb, 0, (size_t)NGRAPH * HDIM * 4, stream);

    count_kernel<<<NB_E, 256, 0, stream>>>(src, dst, et, cnt, blockHist, cntD);
    scan_kernel<<<1, 1024, 0, stream>>>(blockHist, baseArr, relStartA, relTotA,
                                        pbStartA, relOfBlk, npb);
    scan_dst<<<1, 1024, 0, stream>>>(cntD, startD, cursorD);
    scatter_sorted<<<NB_E, 256, 0, stream>>>(src, dst, et, baseArr, perm, cursorD, pofq);

    cvt_rows<<<(N_NODES * 128 / 8 + 255) / 256, 256, 0, stream>>>(x, xb, N_NODES * 128 / 8, 0);
    cvt_wT<<<(NREL * 256 * 16 + 255) / 256, 256, 0, stream>>>(W1, w1b, NREL, 128, 256);
    cvt_wT<<<(NREL * 256 * 32 + 255) / 256, 256, 0, stream>>>(W2, w2b, NREL, 256, 256);
    cvt_wT<<<(256 * 16 + 255) / 256, 256, 0, stream>>>(root1, r1b, 1, 128, 256);
    cvt_wT<<<(256 * 32 + 255) / 256, 256, 0, stream>>>(root2, r2b, 1, 256, 256);

    const int grid_init = (N_NODES + MB - 1) / MB;  // 782

    if (fast) {
        // layer 1: init (bf16) + edge msgs + gather-reduce -> h1b (relu bf16)
        mfma_gemm<128, 2><<<grid_init, 256, 0, stream>>>(xb, r1b, b1, nullptr, hinit,
            nullptr, nullptr, nullptr, nullptr, nullptr, nullptr, nullptr, nullptr, nullptr, nullptr);
        mfma_gemm<128, 3><<<MAX_PB, 256, 0, stream>>>(xb, w1b, nullptr, nullptr, msg,
            perm, src, dst, et, cnt, relOfBlk, pbStartA, relStartA, relTotA, npb);
        reduce_kernel<0><<<N_NODES / 16, 256, 0, stream>>>(hinit, msg, pofq, startD, cntD,
            h1b, nullptr, nullptr, nullptr, nullptr);
        // layer 2: init (bf16) + edge msgs + gather-reduce fused with pooling
        mfma_gemm<256, 2><<<grid_init, 256, 0, stream>>>(h1b, r2b, b2, nullptr, hinit,
            nullptr, nullptr, nullptr, nullptr, nullptr, nullptr, nullptr, nullptr, nullptr, nullptr);
        mfma_gemm<256, 3><<<MAX_PB, 256, 0, stream>>>(h1b, w2b, nullptr, nullptr, msg,
            perm, src, dst, et, cnt, relOfBlk, pbStartA, relStartA, relTotA, npb);
        reduce_kernel<1><<<N_NODES / 16, 256, 0, stream>>>(hinit, msg, pofq, startD, cntD,
            nullptr, batch, wsw, wsb, emb);
    } else {
        // round-3 proven path
        mfma_gemm<128, 0><<<grid_init, 256, 0, stream>>>(xb, r1b, b1, hf, nullptr,
            nullptr, nullptr, nullptr, nullptr, nullptr, nullptr, nullptr, nullptr, nullptr, nullptr);
        mfma_gemm<128, 1><<<MAX_PB, 256, 0, stream>>>(xb, w1b, nullptr, hf, nullptr,
            perm, src, dst, et, cnt, relOfBlk, pbStartA, relStartA, relTotA, npb);
        cvt_rows<<<(N_NODES * HDIM / 8 + 255) / 256, 256, 0, stream>>>(hf, h1b, N_NODES * HDIM / 8, 1);
        mfma_gemm<256, 0><<<grid_init, 256, 0, stream>>>(h1b, r2b, b2, hf, nullptr,
            nullptr, nullptr, nullptr, nullptr, nullptr, nullptr, nullptr, nullptr, nullptr, nullptr);
        mfma_gemm<256, 1><<<MAX_PB, 256, 0, stream>>>(h1b, w2b, nullptr, hf, nullptr,
            perm, src, dst, et, cnt, relOfBlk, pbStartA, relStartA, relTotA, npb);
        pool_kernel<<<N_NODES, 256, 0, stream>>>(hf, batch, wsw, wsb, emb);
    }
    mlp_kernel<<<NGRAPH, 64, 0, stream>>>(emb, m1w, m1b, m2w, m2b, m3w, m3b, ow, ob, (float*)d_out);
}

// Round 5
// 463.631 us; speedup vs baseline: 4.6997x; 1.4156x over previous
//
#include <hip/hip_runtime.h>
#include <math.h>

#define N_NODES 50000
#define E_REAL  200000
#define E_MEAN  250000   // real edges + self-loops (relation 0)
#define NREL    65
#define HDIM    256
#define NGRAPH  1600
#define NB_E    ((E_MEAN + 255) / 256)   // 977 blocks over edges
#define TOT_HIST (NREL * NB_E)           // 63505
#define MB      64                        // rows per MFMA block
#define MAX_PB  4096                      // upper bound on padded edge blocks

typedef __attribute__((ext_vector_type(8))) short short8;   // 8 bf16 (4 VGPRs)
typedef __attribute__((ext_vector_type(4))) float floatx4;  // MFMA C/D frag

__device__ __forceinline__ unsigned short f2bf(float f) {
    unsigned int u = __float_as_uint(f);
    unsigned int r = u + 0x7FFFu + ((u >> 16) & 1u);  // RNE
    return (unsigned short)(r >> 16);
}
__device__ __forceinline__ float bf2f(unsigned short u) {
    return __uint_as_float(((unsigned int)u) << 16);
}

// decode combined edge id: [0,E_REAL) real edges, [E_REAL,E_MEAN) self loops (rel 0)
__device__ __forceinline__ void decode_edge(int e, const int* __restrict__ src,
                                            const int* __restrict__ dst,
                                            const int* __restrict__ et,
                                            int& s, int& d, int& r) {
    if (e < E_REAL) { s = src[e]; d = dst[e]; r = et[e]; }
    else            { s = d = e - E_REAL; r = 0; }
}

__global__ void count_kernel(const int* __restrict__ src, const int* __restrict__ dst,
                             const int* __restrict__ et, int* __restrict__ cnt,
                             int* __restrict__ blockHist, int* __restrict__ cntD) {
    __shared__ int lhist[NREL];
    int t = threadIdx.x;
    if (t < NREL) lhist[t] = 0;
    __syncthreads();
    int e = blockIdx.x * blockDim.x + t;
    if (e < E_MEAN) {
        int s, d, r; decode_edge(e, src, dst, et, s, d, r);
        atomicAdd(&cnt[d * NREL + r], 1);
        atomicAdd(&cntD[d], 1);
        atomicAdd(&lhist[r], 1);
    }
    __syncthreads();
    if (t < NREL) blockHist[t * NB_E + blockIdx.x] = lhist[t];
}

// hierarchical exclusive scan, phase 1: per-block (1024 elems) partial sums.
// grid = 64 blocks x 1024 threads covers n <= 65536, fully coalesced.
__global__ void scan_part(const int* __restrict__ in, int* __restrict__ psum, int n) {
    __shared__ int red[1024];
    int t = threadIdx.x;
    int g = blockIdx.x * 1024 + t;
    red[t] = (g < n) ? in[g] : 0;
    __syncthreads();
    for (int off = 512; off >= 1; off >>= 1) {
        if (t < off) red[t] += red[t + off];
        __syncthreads();
    }
    if (t == 0) psum[blockIdx.x] = red[0];
}

// phase 2: block offset (wave-scan of 64 partials) + block-local Hillis-Steele
// exclusive scan, coalesced write. out2 (optional) gets a second copy (cursor).
__global__ void scan_apply(const int* __restrict__ in, const int* __restrict__ psum,
                           int* __restrict__ out, int* __restrict__ out2, int n) {
    __shared__ int sums[1024];
    __shared__ int soff;
    int t = threadIdx.x;
    int b = blockIdx.x;
    int g = b * 1024 + t;
    if (t < 64) {
        int v = (t < b) ? psum[t] : 0;
        for (int off = 32; off >= 1; off >>= 1) v += __shfl_down(v, off, 64);
        if (t == 0) soff = v;
    }
    int v = (g < n) ? in[g] : 0;
    sums[t] = v;
    __syncthreads();
    for (int off = 1; off < 1024; off <<= 1) {
        int u = (t >= off) ? sums[t - off] : 0;
        __syncthreads();
        sums[t] += u;
        __syncthreads();
    }
    if (g < n) {
        int excl = soff + sums[t] - v;   // exclusive = inclusive - own
        out[g] = excl;
        if (out2) out2[g] = excl;
    }
}

// relation segment metadata from the scanned blockHist (baseArr)
__global__ void meta_kernel(const int* __restrict__ baseArr,
                            int* __restrict__ relStart, int* __restrict__ relTot,
                            int* __restrict__ pBlockStart, int* __restrict__ relOfBlock,
                            int* __restrict__ npb) {
    __shared__ int sStart[NREL + 1];
    __shared__ int sPB[NREL + 1];
    int t = threadIdx.x;
    if (t < NREL) sStart[t] = baseArr[t * NB_E];
    if (t == 0) sStart[NREL] = E_MEAN;
    __syncthreads();
    if (t < NREL) {
        relStart[t] = sStart[t];
        relTot[t] = sStart[t + 1] - sStart[t];
    }
    if (t == 0) {
        int a2 = 0;
        for (int r = 0; r < NREL; ++r) {
            sPB[r] = a2;
            int tot = sStart[r + 1] - sStart[r];
            a2 += (tot + MB - 1) / MB;
        }
        sPB[NREL] = a2;
        npb[0] = a2;
    }
    __syncthreads();
    if (t < NREL) pBlockStart[t] = sPB[t];
    int NPB = sPB[NREL];
    for (int b = t; b < NPB; b += 1024) {
        int lo = 0, hi = NREL - 1;
        while (lo < hi) { int mid = (lo + hi + 1) >> 1; if (sPB[mid] <= b) lo = mid; else hi = mid - 1; }
        relOfBlock[b] = lo;
    }
}

// counting-sort scatter by relation; also build dst-sorted slot -> rel-sorted pos
__global__ void scatter_sorted(const int* __restrict__ src, const int* __restrict__ dst,
                               const int* __restrict__ et, const int* __restrict__ base,
                               int* __restrict__ perm, int* __restrict__ cursorD,
                               int* __restrict__ pofq) {
    __shared__ int lhist[NREL];
    int t = threadIdx.x;
    int b = blockIdx.x;
    if (t < NREL) lhist[t] = 0;
    __syncthreads();
    int e = b * 256 + t;
    if (e < E_MEAN) {
        int s, d, r; decode_edge(e, src, dst, et, s, d, r);
        int local = atomicAdd(&lhist[r], 1);
        int p = base[r * NB_E + b] + local;
        perm[p] = e;
        int q = atomicAdd(&cursorD[d], 1);
        pofq[q] = p;
    }
}

// fp32 row-major -> bf16 row-major, optional relu. One thread per 8 elems.
__global__ void cvt_rows(const float* __restrict__ in, unsigned short* __restrict__ out,
                         int nchunk, int relu) {
    int i = blockIdx.x * 256 + threadIdx.x;
    if (i >= nchunk) return;
    const float4* p = (const float4*)in + (size_t)i * 2;
    float4 a = p[0], b = p[1];
    float v[8] = {a.x, a.y, a.z, a.w, b.x, b.y, b.z, b.w};
    short8 o;
#pragma unroll
    for (int j = 0; j < 8; ++j) {
        float f = relu ? fmaxf(v[j], 0.f) : v[j];
        o[j] = (short)f2bf(f);
    }
    ((short8*)out)[i] = o;
}

// W fp32 [R][K][N] -> bf16 [R][N][K]
__global__ void cvt_wT(const float* __restrict__ W, unsigned short* __restrict__ out,
                       int R, int K, int N) {
    int kc8 = K / 8;
    int total = R * N * kc8;
    int i = blockIdx.x * 256 + threadIdx.x;
    if (i >= total) return;
    int kc = i % kc8;
    int tmp = i / kc8;
    int n = tmp % N;
    int r = tmp / N;
    const float* src = W + ((size_t)r * K + kc * 8) * N + n;
    short8 o;
#pragma unroll
    for (int j = 0; j < 8; ++j) o[j] = (short)f2bf(src[(size_t)j * N]);
    ((short8*)out)[i] = o;
}

// MFMA GEMM: 64 rows x 256 cols per block, 4 waves (each 64x64).
// MODE 0: INIT dense rows -> fp32 out + bias (fallback)
// MODE 1: EDGE gathered rows -> weighted fp32 atomic scatter (fallback)
// MODE 2: INIT dense rows -> bf16 out + bias (via LDS repack, coalesced)
// MODE 3: EDGE gathered rows -> weighted bf16 msg rows (via LDS repack)
template<int K, int MODE>
__global__ __launch_bounds__(256) void mfma_gemm(
    const unsigned short* __restrict__ A,   // [*][K] bf16 rows
    const unsigned short* __restrict__ B,   // [R][256][K] bf16 (transposed)
    const float* __restrict__ bias,
    float* __restrict__ outF,
    unsigned short* __restrict__ outB,
    const int* __restrict__ perm, const int* __restrict__ srcA,
    const int* __restrict__ dstA, const int* __restrict__ etA,
    const int* __restrict__ cnt,
    const int* __restrict__ relOfBlock, const int* __restrict__ pBlockStart,
    const int* __restrict__ relStart, const int* __restrict__ relTot,
    const int* __restrict__ npb)
{
    constexpr bool EDGE = (MODE == 1 || MODE == 3);
    constexpr int CH = K / 8;                 // 16B chunks per row
    __shared__ __align__(16) unsigned short lds[MB * HDIM];  // A staging (MB*K) / repack (MB*256)
    __shared__ int ssrc[MB];
    __shared__ int sdst[MB];
    __shared__ float sw[MB];
    int t = threadIdx.x;
    int b = blockIdx.x;
    int rel = 0, rowbase = 0, jb = 0, rs = 0, nval = MB;
    if constexpr (EDGE) {
        if (b >= npb[0]) return;
        rel = relOfBlock[b];
        jb = b - pBlockStart[rel];
        rs = relStart[rel];
        nval = relTot[rel] - jb * MB; if (nval > MB) nval = MB;
        if (t < MB) {
            int s = 0, d = 0; float w = 0.f;
            if (t < nval) {
                int e = perm[rs + jb * MB + t];
                int rr; decode_edge(e, srcA, dstA, etA, s, d, rr);
                w = 1.0f / (float)cnt[d * NREL + rel];
            }
            ssrc[t] = s; sdst[t] = d; sw[t] = w;
        }
        __syncthreads();
    } else {
        rowbase = b * MB;
    }
    // stage A rows into LDS, XOR-swizzled 16B chunks (c ^= row&7)
    for (int q = t; q < MB * CH; q += 256) {
        int row = q / CH, c = q % CH;
        int srow;
        if constexpr (EDGE) srow = ssrc[row];
        else { srow = rowbase + row; if (srow >= N_NODES) srow = N_NODES - 1; }
        uint4 v = *(const uint4*)(A + (size_t)srow * K + c * 8);
        *(uint4*)((char*)lds + row * (K * 2) + ((c ^ (row & 7)) * 16)) = v;
    }
    __syncthreads();

    int wave = t >> 6, lane = t & 63;
    int n0 = wave * 64;
    int lrow = lane & 15;
    int lk = lane >> 4;
    floatx4 acc[4][4];
#pragma unroll
    for (int mf = 0; mf < 4; ++mf)
#pragma unroll
        for (int nf = 0; nf < 4; ++nf) acc[mf][nf] = (floatx4)0.f;

    const unsigned short* Bp = B + ((size_t)rel * HDIM + n0) * K;
    constexpr int KS = K / 32;
    short8 b_cur[4], b_nxt[4];
#pragma unroll
    for (int nf = 0; nf < 4; ++nf)
        b_cur[nf] = *(const short8*)(Bp + (size_t)(nf * 16 + lrow) * K + lk * 8);
#pragma unroll
    for (int ks = 0; ks < KS; ++ks) {
        short8 a[4];
#pragma unroll
        for (int mf = 0; mf < 4; ++mf) {
            int row = mf * 16 + lrow;
            int c = (ks * 4 + lk) ^ (row & 7);
            a[mf] = *(const short8*)((const char*)lds + row * (K * 2) + c * 16);
        }
        if (ks + 1 < KS) {
#pragma unroll
            for (int nf = 0; nf < 4; ++nf)
                b_nxt[nf] = *(const short8*)(Bp + (size_t)(nf * 16 + lrow) * K + (ks + 1) * 32 + lk * 8);
        }
#pragma unroll
        for (int mf = 0; mf < 4; ++mf)
#pragma unroll
            for (int nf = 0; nf < 4; ++nf)
                acc[mf][nf] = __builtin_amdgcn_mfma_f32_16x16x32_bf16(a[mf], b_cur[nf], acc[mf][nf], 0, 0, 0);
#pragma unroll
        for (int nf = 0; nf < 4; ++nf) b_cur[nf] = b_nxt[nf];
    }

    // C/D layout: col = lane&15, row = (lane>>4)*4 + reg
    if constexpr (MODE == 1) {
#pragma unroll
        for (int mf = 0; mf < 4; ++mf) {
            int mbase = mf * 16 + lk * 4;
#pragma unroll
            for (int i = 0; i < 4; ++i) {
                int mm = mbase + i;
                float w = sw[mm];
                if (w != 0.f) {
                    int drow = sdst[mm];
#pragma unroll
                    for (int nf = 0; nf < 4; ++nf) {
                        int col = n0 + nf * 16 + lrow;
                        atomicAdd(&outF[(size_t)drow * HDIM + col], acc[mf][nf][i] * w);
                    }
                }
            }
        }
    } else if constexpr (MODE == 0) {
        float bv[4];
#pragma unroll
        for (int nf = 0; nf < 4; ++nf) bv[nf] = bias[n0 + nf * 16 + lrow];
#pragma unroll
        for (int mf = 0; mf < 4; ++mf) {
            int mbase = mf * 16 + lk * 4;
#pragma unroll
            for (int i = 0; i < 4; ++i) {
                int mm = rowbase + mbase + i;
                if (mm < N_NODES) {
#pragma unroll
                    for (int nf = 0; nf < 4; ++nf) {
                        int col = n0 + nf * 16 + lrow;
                        outF[(size_t)mm * HDIM + col] = acc[mf][nf][i] + bv[nf];
                    }
                }
            }
        }
    } else {
        // MODE 2 / 3: repack to bf16 in LDS, then coalesced row stores
        float bv[4];
        if constexpr (MODE == 2) {
#pragma unroll
            for (int nf = 0; nf < 4; ++nf) bv[nf] = bias[n0 + nf * 16 + lrow];
        }
        __syncthreads();  // A staging reads done; reuse lds
#pragma unroll
        for (int mf = 0; mf < 4; ++mf) {
            int mbase = mf * 16 + lk * 4;
#pragma unroll
            for (int i = 0; i < 4; ++i) {
                int row = mbase + i;
                float w = (MODE == 3) ? sw[row] : 0.f;
#pragma unroll
                for (int nf = 0; nf < 4; ++nf) {
                    int col = n0 + nf * 16 + lrow;
                    float v = acc[mf][nf][i];
                    if constexpr (MODE == 3) v *= w;
                    else v += bv[nf];
                    lds[row * HDIM + col] = f2bf(v);
                }
            }
        }
        __syncthreads();
        int limit;
        size_t rb;
        if constexpr (MODE == 3) { limit = nval; rb = (size_t)rs + (size_t)jb * MB; }
        else { limit = N_NODES - rowbase; if (limit > MB) limit = MB; rb = (size_t)rowbase; }
        for (int q = t; q < limit * 32; q += 256) {
            int row = q >> 5, c = q & 31;
            *(uint4*)(outB + (rb + row) * HDIM + c * 8) = *(const uint4*)(lds + row * HDIM + c * 8);
        }
    }
}

// gather-reduce messages per dst. FUSE_POOL=0: h1b = relu(init+sum) bf16.
// FUSE_POOL=1: v = relu(init+sum); pool -> emb atomics (h2 never materialized).
template<int FUSE_POOL>
__global__ void reduce_kernel(const unsigned short* __restrict__ hinit,
                              const unsigned short* __restrict__ msg,
                              const int* __restrict__ pofq, const int* __restrict__ startD,
                              const int* __restrict__ cntD,
                              unsigned short* __restrict__ h1b,
                              const int* __restrict__ batch, const float* __restrict__ wsw,
                              const float* __restrict__ wsb, float* __restrict__ emb) {
    int t = threadIdx.x;
    int d0 = blockIdx.x * 16;
    __shared__ float red[4];
    __shared__ float ssig;
    for (int j = 0; j < 16; ++j) {
        int d = d0 + j;
        int s0 = startD[d], n = cntD[d];
        float acc = 0.f;
        for (int q = 0; q < n; ++q) {
            int p = pofq[s0 + q];
            acc += bf2f(msg[(size_t)p * HDIM + t]);
        }
        float v = bf2f(hinit[(size_t)d * HDIM + t]) + acc;
        v = fmaxf(v, 0.f);
        if constexpr (FUSE_POOL == 0) {
            h1b[(size_t)d * HDIM + t] = f2bf(v);
        } else {
            float p = v * wsw[t];
            for (int off = 32; off >= 1; off >>= 1) p += __shfl_down(p, off, 64);
            if ((t & 63) == 0) red[t >> 6] = p;
            __syncthreads();
            if (t == 0) {
                float s = red[0] + red[1] + red[2] + red[3] + wsb[0];
                ssig = 1.0f / (1.0f + expf(-s));
            }
            __syncthreads();
            atomicAdd(&emb[(size_t)batch[d] * HDIM + t], ssig * v);
            __syncthreads();
        }
    }
}

// fallback pool (fp32 h input)
__global__ void pool_kernel(const float* __restrict__ h, const int* __restrict__ batch,
                            const float* __restrict__ wsw, const float* __restrict__ wsb,
                            float* __restrict__ emb) {
    int i = blockIdx.x;
    int t = threadIdx.x;
    float v = fmaxf(h[(size_t)i * HDIM + t], 0.f);
    float p = v * wsw[t];
    for (int off = 32; off >= 1; off >>= 1) p += __shfl_down(p, off, 64);
    __shared__ float red[4];
    __shared__ float ssig;
    if ((t & 63) == 0) red[t >> 6] = p;
    __syncthreads();
    if (t == 0) {
        float s = red[0] + red[1] + red[2] + red[3] + wsb[0];
        ssig = 1.0f / (1.0f + expf(-s));
    }
    __syncthreads();
    atomicAdd(&emb[(size_t)batch[i] * HDIM + t], ssig * v);
}

__global__ void mlp_kernel(const float* __restrict__ emb,
                           const float* __restrict__ m1w, const float* __restrict__ m1b,
                           const float* __restrict__ m2w, const float* __restrict__ m2b,
                           const float* __restrict__ m3w, const float* __restrict__ m3b,
                           const float* __restrict__ ow,  const float* __restrict__ ob,
                           float* __restrict__ out) {
    int g = blockIdx.x;
    int t = threadIdx.x; // 64 threads = 1 wave
    __shared__ float e[HDIM];
    __shared__ float z1[64], z2[64];
    for (int idx = t; idx < HDIM; idx += 64) e[idx] = emb[(size_t)g * HDIM + idx];
    __syncthreads();
    float a = m1b[t];
    for (int k = 0; k < HDIM; ++k) a += e[k] * m1w[k * 64 + t];
    z1[t] = fmaxf(a, 0.f);
    __syncthreads();
    a = m2b[t];
    for (int k = 0; k < 64; ++k) a += z1[k] * m2w[k * 64 + t];
    z2[t] = fmaxf(a, 0.f);
    __syncthreads();
    a = m3b[t];
    for (int k = 0; k < 64; ++k) a += z2[k] * m3w[k * 64 + t];
    float p = a * ow[t];
    for (int off = 32; off >= 1; off >>= 1) p += __shfl_down(p, off, 64);
    if (t == 0) out[g] = p + ob[0];
}

extern "C" void kernel_launch(void* const* d_in, const int* in_sizes, int n_in,
                              void* d_out, int out_size, void* d_ws, size_t ws_size,
                              hipStream_t stream) {
    const float* x     = (const float*)d_in[0];
    const int*   ei    = (const int*)d_in[1];
    const int*   src   = ei;
    const int*   dst   = ei + E_REAL;
    const int*   et    = (const int*)d_in[2];
    const int*   batch = (const int*)d_in[3];
    const float* W1    = (const float*)d_in[4];
    const float* root1 = (const float*)d_in[5];
    const float* b1    = (const float*)d_in[6];
    const float* W2    = (const float*)d_in[7];
    const float* root2 = (const float*)d_in[8];
    const float* b2    = (const float*)d_in[9];
    const float* wsw   = (const float*)d_in[10];
    const float* wsb   = (const float*)d_in[11];
    const float* m1w   = (const float*)d_in[12];
    const float* m1b   = (const float*)d_in[13];
    const float* m2w   = (const float*)d_in[14];
    const float* m2b   = (const float*)d_in[15];
    const float* m3w   = (const float*)d_in[16];
    const float* m3b   = (const float*)d_in[17];
    const float* ow    = (const float*)d_in[18];
    const float* ob    = (const float*)d_in[19];

    char* ws = (char*)d_ws;
    size_t off = 0;
    auto alloc = [&](size_t bytes) {
        void* p = ws + off;
        off = (off + bytes + 255) & ~(size_t)255;
        return p;
    };
    // common buffers
    int*   cnt       = (int*)alloc((size_t)N_NODES * NREL * 4);     // 13.0 MB
    int*   blockHist = (int*)alloc((size_t)TOT_HIST * 4);
    int*   baseArr   = (int*)alloc((size_t)TOT_HIST * 4);
    int*   perm      = (int*)alloc((size_t)E_MEAN * 4);             // 1.0 MB
    int*   relStartA = (int*)alloc(NREL * 4);
    int*   relTotA   = (int*)alloc(NREL * 4);
    int*   pbStartA  = (int*)alloc(NREL * 4);
    int*   relOfBlk  = (int*)alloc(MAX_PB * 4);
    int*   npb       = (int*)alloc(4);
    int*   psumA     = (int*)alloc(64 * 4);
    int*   psumB     = (int*)alloc(64 * 4);
    unsigned short* xb  = (unsigned short*)alloc((size_t)N_NODES * 128 * 2);    // 12.8 MB
    unsigned short* w1b = (unsigned short*)alloc((size_t)NREL * 256 * 128 * 2); // 4.3 MB
    unsigned short* w2b = (unsigned short*)alloc((size_t)NREL * 256 * 256 * 2); // 8.5 MB
    unsigned short* r1b = (unsigned short*)alloc((size_t)256 * 128 * 2);
    unsigned short* r2b = (unsigned short*)alloc((size_t)256 * 256 * 2);
    unsigned short* h1b = (unsigned short*)alloc((size_t)N_NODES * HDIM * 2);   // 25.6 MB
    float* emb = (float*)alloc((size_t)NGRAPH * HDIM * 4);                       // 1.6 MB
    size_t off_common = off;

    // fast-path extras
    unsigned short* hinit = (unsigned short*)alloc((size_t)N_NODES * HDIM * 2); // 25.6 MB
    unsigned short* msg   = (unsigned short*)alloc((size_t)E_MEAN * HDIM * 2);  // 128 MB
    int* pofq    = (int*)alloc((size_t)E_MEAN * 4);
    int* cntD    = (int*)alloc((size_t)N_NODES * 4);
    int* startD  = (int*)alloc((size_t)N_NODES * 4);
    int* cursorD = (int*)alloc((size_t)N_NODES * 4);
    size_t need_fast = off;

    float* hf = nullptr;
    bool fast = (ws_size >= need_fast);
    if (!fast) {
        // fallback layout: round-3 proven footprint; dst structures alias hf
        off = off_common;
        hf = (float*)alloc((size_t)N_NODES * HDIM * 4);  // 51.2 MB
        char* hh = (char*)hf;
        pofq    = (int*)hh;                                 hh += (size_t)E_MEAN * 4;
        cntD    = (int*)hh;                                 hh += (size_t)N_NODES * 4;
        startD  = (int*)hh;                                 hh += (size_t)N_NODES * 4;
        cursorD = (int*)hh;
        hinit = h1b;  // unused sink
        msg = h1b;    // unused sink
    }

    hipMemsetAsync(cnt, 0, (size_t)N_NODES * NREL * 4, stream);
    hipMemsetAsync(cntD, 0, (size_t)N_NODES * 4, stream);
    hipMemsetAsync(emb, 0, (size_t)NGRAPH * HDIM * 4, stream);

    count_kernel<<<NB_E, 256, 0, stream>>>(src, dst, et, cnt, blockHist, cntD);
    // hierarchical scans (coalesced, all-CU) replacing the single-block scans
    scan_part<<<64, 1024, 0, stream>>>(blockHist, psumA, TOT_HIST);
    scan_apply<<<64, 1024, 0, stream>>>(blockHist, psumA, baseArr, nullptr, TOT_HIST);
    meta_kernel<<<1, 1024, 0, stream>>>(baseArr, relStartA, relTotA, pbStartA, relOfBlk, npb);
    scan_part<<<64, 1024, 0, stream>>>(cntD, psumB, N_NODES);
    scan_apply<<<64, 1024, 0, stream>>>(cntD, psumB, startD, cursorD, N_NODES);
    scatter_sorted<<<NB_E, 256, 0, stream>>>(src, dst, et, baseArr, perm, cursorD, pofq);

    cvt_rows<<<(N_NODES * 128 / 8 + 255) / 256, 256, 0, stream>>>(x, xb, N_NODES * 128 / 8, 0);
    cvt_wT<<<(NREL * 256 * 16 + 255) / 256, 256, 0, stream>>>(W1, w1b, NREL, 128, 256);
    cvt_wT<<<(NREL * 256 * 32 + 255) / 256, 256, 0, stream>>>(W2, w2b, NREL, 256, 256);
    cvt_wT<<<(256 * 16 + 255) / 256, 256, 0, stream>>>(root1, r1b, 1, 128, 256);
    cvt_wT<<<(256 * 32 + 255) / 256, 256, 0, stream>>>(root2, r2b, 1, 256, 256);

    const int grid_init = (N_NODES + MB - 1) / MB;  // 782

    if (fast) {
        // layer 1: init (bf16) + edge msgs + gather-reduce -> h1b (relu bf16)
        mfma_gemm<128, 2><<<grid_init, 256, 0, stream>>>(xb, r1b, b1, nullptr, hinit,
            nullptr, nullptr, nullptr, nullptr, nullptr, nullptr, nullptr, nullptr, nullptr, nullptr);
        mfma_gemm<128, 3><<<MAX_PB, 256, 0, stream>>>(xb, w1b, nullptr, nullptr, msg,
            perm, src, dst, et, cnt, relOfBlk, pbStartA, relStartA, relTotA, npb);
        reduce_kernel<0><<<N_NODES / 16, 256, 0, stream>>>(hinit, msg, pofq, startD, cntD,
            h1b, nullptr, nullptr, nullptr, nullptr);
        // layer 2: init (bf16) + edge msgs + gather-reduce fused with pooling
        mfma_gemm<256, 2><<<grid_init, 256, 0, stream>>>(h1b, r2b, b2, nullptr, hinit,
            nullptr, nullptr, nullptr, nullptr, nullptr, nullptr, nullptr, nullptr, nullptr, nullptr);
        mfma_gemm<256, 3><<<MAX_PB, 256, 0, stream>>>(h1b, w2b, nullptr, nullptr, msg,
            perm, src, dst, et, cnt, relOfBlk, pbStartA, relStartA, relTotA, npb);
        reduce_kernel<1><<<N_NODES / 16, 256, 0, stream>>>(hinit, msg, pofq, startD, cntD,
            nullptr, batch, wsw, wsb, emb);
    } else {
        // round-3 proven path
        mfma_gemm<128, 0><<<grid_init, 256, 0, stream>>>(xb, r1b, b1, hf, nullptr,
            nullptr, nullptr, nullptr, nullptr, nullptr, nullptr, nullptr, nullptr, nullptr, nullptr);
        mfma_gemm<128, 1><<<MAX_PB, 256, 0, stream>>>(xb, w1b, nullptr, hf, nullptr,
            perm, src, dst, et, cnt, relOfBlk, pbStartA, relStartA, relTotA, npb);
        cvt_rows<<<(N_NODES * HDIM / 8 + 255) / 256, 256, 0, stream>>>(hf, h1b, N_NODES * HDIM / 8, 1);
        mfma_gemm<256, 0><<<grid_init, 256, 0, stream>>>(h1b, r2b, b2, hf, nullptr,
            nullptr, nullptr, nullptr, nullptr, nullptr, nullptr, nullptr, nullptr, nullptr, nullptr);
        mfma_gemm<256, 1><<<MAX_PB, 256, 0, stream>>>(h1b, w2b, nullptr, hf, nullptr,
            perm, src, dst, et, cnt, relOfBlk, pbStartA, relStartA, relTotA, npb);
        pool_kernel<<<N_NODES, 256, 0, stream>>>(hf, batch, wsw, wsb, emb);
    }
    mlp_kernel<<<NGRAPH, 64, 0, stream>>>(emb, m1w, m1b, m2w, m2b, m3w, m3b, ow, ob, (float*)d_out);
}